// Round 13
// baseline (578.959 us; speedup 1.0000x reference)
//
#include <hip/hip_runtime.h>
#include <hip/hip_fp16.h>

#define NN 100000
#define NE 1600000
#define NBK 196       // ceil(100000/512) dst buckets (512 nodes each)
#define CAP 10240     // per-bucket edge capacity
#define EPB 8192      // edges per block in k_bin
#define NWAVES 8192   // wave count for k_vmm/k_mlp (grid-stride, streaming)
#define RB 128        // k_red1 blocks (P partial reduce)
#define SB 256        // k_stat blocks (direct matrix stats)

// ---------------- pass 1: bin edges by dst>>9, packed (src<<9)|dst_local ----------------
__global__ __launch_bounds__(256) void k_bin(const int* __restrict__ src,
                                             const int* __restrict__ dst,
                                             int* __restrict__ gcnt,
                                             unsigned int* __restrict__ binned, int E) {
  __shared__ int bcnt[256];
  const int t = threadIdx.x;
  const int e0 = blockIdx.x * EPB;
  bcnt[t] = 0;
  __syncthreads();
  for (int i = 0; i < EPB; i += 256) {
    int e = e0 + i + t;
    if (e < E) atomicAdd(&bcnt[dst[e] >> 9], 1);
  }
  __syncthreads();
  if (t < NBK) {
    int c = bcnt[t];
    bcnt[t] = c ? atomicAdd(&gcnt[t], c) : 0;
  }
  __syncthreads();
  for (int i = 0; i < EPB; i += 256) {
    int e = e0 + i + t;
    if (e < E) {
      int d = dst[e];
      int b = d >> 9;
      int pos = atomicAdd(&bcnt[b], 1);
      if (pos < CAP) binned[(size_t)b * CAP + pos] = ((unsigned int)src[e] << 9) | (d & 511);
    }
  }
}

// ---------------- pass 2: per-bucket local CSR (block-local writes) ----------------
__global__ __launch_bounds__(512) void k_csr(const unsigned int* __restrict__ binned,
                                             const int* __restrict__ gcnt,
                                             int* __restrict__ rowbeg,
                                             int* __restrict__ rowend,
                                             int* __restrict__ eidx, int N) {
  __shared__ int hist[512];
  __shared__ int cur[512];
  const int t = threadIdx.x;
  const int b = blockIdx.x;
  const size_t base = (size_t)b * CAP;
  int cnt = gcnt[b];
  if (cnt > CAP) cnt = CAP;
  hist[t] = 0;
  __syncthreads();
  for (int e = t; e < cnt; e += 512) atomicAdd(&hist[binned[base + e] & 511], 1);
  __syncthreads();
  const int own = hist[t];
  for (int o = 1; o < 512; o <<= 1) {
    int x = (t >= o) ? hist[t - o] : 0;
    __syncthreads();
    hist[t] += x;
    __syncthreads();
  }
  const int incl = hist[t];
  const int excl = incl - own;
  const int node = b * 512 + t;
  if (node < N) {
    rowbeg[node] = (int)base + excl;
    rowend[node] = (int)base + incl;
  }
  cur[t] = excl;
  __syncthreads();
  for (int e = t; e < cnt; e += 512) {
    unsigned int pk = binned[base + e];
    int pos = atomicAdd(&cur[pk & 511], 1);
    eidx[base + pos] = (int)(pk >> 9);
  }
}

// ------- k_stat: column sum/sumsq of M[N][64] -> PB[SB][128] f64, coalesced + ILP-4 -------
__global__ __launch_bounds__(256) void k_stat(const float* __restrict__ M, int N,
                                              double* __restrict__ PB) {
  const int t = threadIdx.x;
  const int c = t & 63;
  const int rr = t >> 6;  // 0..3
  const int j = blockIdx.x;
  const int STR = SB * 4;  // 1024 rows per sweep
  double s0 = 0, s1 = 0, s2 = 0, s3 = 0, q0 = 0, q1 = 0, q2 = 0, q3 = 0;
  int r = j * 4 + rr;
  for (; r + 3 * STR < N; r += 4 * STR) {
    float v0 = M[(size_t)r * 64 + c];
    float v1 = M[(size_t)(r + STR) * 64 + c];
    float v2 = M[(size_t)(r + 2 * STR) * 64 + c];
    float v3 = M[(size_t)(r + 3 * STR) * 64 + c];
    s0 += v0; q0 = fma((double)v0, (double)v0, q0);
    s1 += v1; q1 = fma((double)v1, (double)v1, q1);
    s2 += v2; q2 = fma((double)v2, (double)v2, q2);
    s3 += v3; q3 = fma((double)v3, (double)v3, q3);
  }
  for (; r < N; r += STR) {
    float v = M[(size_t)r * 64 + c];
    s0 += v; q0 = fma((double)v, (double)v, q0);
  }
  __shared__ double rs[256], rq[256];
  rs[t] = (s0 + s1) + (s2 + s3);
  rq[t] = (q0 + q1) + (q2 + q3);
  __syncthreads();
  if (t < 64)
    PB[(size_t)j * 128 + t] = rs[t] + rs[t + 64] + rs[t + 128] + rs[t + 192];
  else if (t < 128) {
    int c2 = t - 64;
    PB[(size_t)j * 128 + 64 + c2] = rq[c2] + rq[c2 + 64] + rq[c2 + 128] + rq[c2 + 192];
  }
}

// ------- k_red1: P[nblk][128] f32 -> PB[RB][128] f64 (for k_mlp's per-wave partials) -------
__global__ __launch_bounds__(256) void k_red1(const float* __restrict__ P, int nblk,
                                              double* __restrict__ PB) {
  const int t = threadIdx.x;
  const int c = t & 127;
  const int half = t >> 7;  // 0 or 1
  const int j = blockIdx.x;
  const int STR = RB * 2;   // 256 rows per sweep
  double a0 = 0.0, a1 = 0.0, a2 = 0.0, a3 = 0.0;
  int r = j * 2 + half;
  for (; r + 3 * STR < nblk; r += 4 * STR) {
    a0 += (double)P[(size_t)r * 128 + c];
    a1 += (double)P[(size_t)(r + STR) * 128 + c];
    a2 += (double)P[(size_t)(r + 2 * STR) * 128 + c];
    a3 += (double)P[(size_t)(r + 3 * STR) * 128 + c];
  }
  for (; r < nblk; r += STR) a0 += (double)P[(size_t)r * 128 + c];
  double acc = (a0 + a1) + (a2 + a3);
  __shared__ double red[256];
  red[t] = acc;
  __syncthreads();
  if (t < 128) PB[(size_t)j * 128 + t] = red[t] + red[t + 128];
}

// ------- k_red2: finish PB[nrows][128], emit BN affine LUT (+ optional e0 = d@W1n) -------
// aff layout: [0..63]=a, [64..127]=d, [128..191]=e0 (only if W1n != null)
__global__ __launch_bounds__(256) void k_red2(const double* __restrict__ PB, int nrows,
                                              const float* __restrict__ g,
                                              const float* __restrict__ bt,
                                              double invN, float* __restrict__ aff,
                                              const float* __restrict__ W1n) {
  const int t = threadIdx.x;
  const int c = t & 127;
  const int half = t >> 7;
  double a0 = 0.0, a1 = 0.0, a2 = 0.0, a3 = 0.0;
  int j = half;
  for (; j + 6 < nrows; j += 8) {
    a0 += PB[(size_t)j * 128 + c];
    a1 += PB[(size_t)(j + 2) * 128 + c];
    a2 += PB[(size_t)(j + 4) * 128 + c];
    a3 += PB[(size_t)(j + 6) * 128 + c];
  }
  for (; j < nrows; j += 2) a0 += PB[(size_t)j * 128 + c];
  __shared__ double st[256];
  __shared__ float sd[64];
  st[t] = (a0 + a1) + (a2 + a3);
  __syncthreads();
  if (t < 128) st[t] = st[t] + st[t + 128];
  __syncthreads();
  if (t < 64) {
    double mu = st[t] * invN;
    double var = st[64 + t] * invN - mu * mu;
    double ai = (double)g[t] / sqrt(var + 1e-5);
    float dv = (float)((double)bt[t] - ai * mu);
    aff[t] = (float)ai;
    aff[64 + t] = dv;
    sd[t] = dv;
  }
  __syncthreads();
  if (W1n && t < 64) {
    float e = 0.f;
#pragma unroll
    for (int k = 0; k < 64; ++k) e = fmaf(sd[k], W1n[k * 64 + t], e);
    aff[128 + t] = e;
  }
}

__device__ __forceinline__ float rdl(float v, int l) {
  return __int_as_float(__builtin_amdgcn_readlane(__float_as_int(v), l));
}

// ========== k_vmm: v = In @ (diag(a)*W1) -> half  (streaming, coalesced) ==========
// XFORM=true scales W row k by aff[k] (outer-BN a); bias handled in gather epilogue.
template <bool XFORM>
__global__ __launch_bounds__(256) void k_vmm(const float* __restrict__ In,
                                             const float* __restrict__ aff,
                                             const float* __restrict__ W,
                                             __half* __restrict__ Outh, int N) {
  const int lane = threadIdx.x & 63;
  const int wid = (blockIdx.x * 256 + threadIdx.x) >> 6;
  const int nw = NWAVES;
  const int G = N >> 2;

  float w[64];
#pragma unroll
  for (int k = 0; k < 64; ++k) {
    float wk = W[k * 64 + lane];
    if (XFORM) wk *= aff[k];
    w[k] = wk;
  }

  int g = wid;
  float4 av = make_float4(0.f, 0.f, 0.f, 0.f);
  if (g < G) av = *(const float4*)(In + (size_t)g * 256 + lane * 4);
  for (; g < G; g += nw) {
    const int gn = g + nw;
    float4 nx = make_float4(0.f, 0.f, 0.f, 0.f);
    if (gn < G) nx = *(const float4*)(In + (size_t)gn * 256 + lane * 4);

    const float a4[4] = {av.x, av.y, av.z, av.w};
    float acc0 = 0.f, acc1 = 0.f, acc2 = 0.f, acc3 = 0.f;
#pragma unroll
    for (int k = 0; k < 64; ++k) {
      const float ak = a4[k & 3];
      const int sl = k >> 2;
      acc0 = fmaf(rdl(ak, sl), w[k], acc0);
      acc1 = fmaf(rdl(ak, 16 + sl), w[k], acc1);
      acc2 = fmaf(rdl(ak, 32 + sl), w[k], acc2);
      acc3 = fmaf(rdl(ak, 48 + sl), w[k], acc3);
    }
    const int r0 = g * 4;
    Outh[(size_t)(r0 + 0) * 64 + lane] = __float2half(acc0);
    Outh[(size_t)(r0 + 1) * 64 + lane] = __float2half(acc1);
    Outh[(size_t)(r0 + 2) * 64 + lane] = __float2half(acc2);
    Outh[(size_t)(r0 + 3) * 64 + lane] = __float2half(acc3);
    av = nx;
  }
}

// ========== k_gather_h: Z[n] = sum_{n ∪ nb} v[m] + cnt_n*e0 + b1  (half rows, 128B) ==========
// Proven gather geometry: 1 node/wave, 4 edge-groups of 16 lanes, unroll-2 (8 loads in
// flight/node). Rows are 64 halfs = 128B; each lane loads uint2 (4 halfs, 8B).
__global__ __launch_bounds__(256) void k_gather_h(const __half* __restrict__ V,
                                                  const int* __restrict__ rowbeg,
                                                  const int* __restrict__ rowend,
                                                  const int* __restrict__ eidx,
                                                  const float* __restrict__ e0,
                                                  const float* __restrict__ b1,
                                                  float* __restrict__ Out, int N) {
  const int node = blockIdx.x * 4 + (threadIdx.x >> 6);
  if (node >= N) return;
  const int lane = threadIdx.x & 63;
  const int grp = lane >> 4;   // edge group 0..3
  const int c4 = lane & 15;    // 4-half column chunk
  const int beg = rowbeg[node], end = rowend[node];

  float4 s = make_float4(0.f, 0.f, 0.f, 0.f);
  float4 s1 = s;
  if (grp == 0) {
    const uint2 raw = *(const uint2*)(V + (size_t)node * 64 + c4 * 4);  // self
    const float2 f0 = __half22float2(*(const __half2*)&raw.x);
    const float2 f1 = __half22float2(*(const __half2*)&raw.y);
    s = make_float4(f0.x, f0.y, f1.x, f1.y);
  }
  int i = beg + grp;
  for (; i + 4 < end; i += 8) {
    const int e0i = eidx[i];
    const int e1i = eidx[i + 4];
    const uint2 r0 = *(const uint2*)(V + (size_t)e0i * 64 + c4 * 4);
    const uint2 r1 = *(const uint2*)(V + (size_t)e1i * 64 + c4 * 4);
    const float2 a0 = __half22float2(*(const __half2*)&r0.x);
    const float2 a1 = __half22float2(*(const __half2*)&r0.y);
    const float2 b0 = __half22float2(*(const __half2*)&r1.x);
    const float2 b1v = __half22float2(*(const __half2*)&r1.y);
    s.x += a0.x; s.y += a0.y; s.z += a1.x; s.w += a1.y;
    s1.x += b0.x; s1.y += b0.y; s1.z += b1v.x; s1.w += b1v.y;
  }
  if (i < end) {
    const uint2 r0 = *(const uint2*)(V + (size_t)eidx[i] * 64 + c4 * 4);
    const float2 a0 = __half22float2(*(const __half2*)&r0.x);
    const float2 a1 = __half22float2(*(const __half2*)&r0.y);
    s.x += a0.x; s.y += a0.y; s.z += a1.x; s.w += a1.y;
  }
  s.x += s1.x; s.y += s1.y; s.z += s1.z; s.w += s1.w;
#pragma unroll
  for (int off = 16; off < 64; off <<= 1) {  // butterfly across the 4 groups
    s.x += __shfl_xor(s.x, off);
    s.y += __shfl_xor(s.y, off);
    s.z += __shfl_xor(s.z, off);
    s.w += __shfl_xor(s.w, off);
  }
  if (grp == 0) {
    float4 o = *(const float4*)(b1 + c4 * 4);
    if (e0) {
      const float4 ev = *(const float4*)(e0 + c4 * 4);
      const float cnt = (float)(end - beg + 1);
      o.x = fmaf(cnt, ev.x, o.x);
      o.y = fmaf(cnt, ev.y, o.y);
      o.z = fmaf(cnt, ev.z, o.z);
      o.w = fmaf(cnt, ev.w, o.w);
    }
    o.x += s.x; o.y += s.y; o.z += s.z; o.w += s.w;
    *(float4*)(Out + (size_t)node * 64 + c4 * 4) = o;
  }
}

// ========== register-resident GEMM2 (per-wave epilogue, no LDS/barriers) ==========
// MODE 1: relu(out), store, stats(relu)   [inner layers]
// MODE 3: log_softmax(out) -> store        [final layer]
template <int OUTC, int MODE>
__global__ __launch_bounds__(256) void k_mlp(const float* __restrict__ In,
                                             const float* __restrict__ aff,
                                             const float* __restrict__ W,
                                             const float* __restrict__ b,
                                             float* __restrict__ Out,
                                             float* __restrict__ P, int N) {
  const int lane = threadIdx.x & 63;
  const int wid = (blockIdx.x * 256 + threadIdx.x) >> 6;
  const int nw = NWAVES;
  const int G = N >> 2;

  const int cc = (lane < OUTC) ? lane : 0;
  float w[64];
#pragma unroll
  for (int k = 0; k < 64; ++k) w[k] = W[k * OUTC + cc];
  const float bias = b[cc];

  const float4 fa = *(const float4*)(aff + (lane & 15) * 4);
  const float4 fd = *(const float4*)(aff + 64 + (lane & 15) * 4);

  float sc = 0.f, qc = 0.f;

  int g = wid;
  float4 av = make_float4(0.f, 0.f, 0.f, 0.f);
  if (g < G) av = *(const float4*)(In + (size_t)g * 256 + lane * 4);
  for (; g < G; g += nw) {
    const int gn = g + nw;
    float4 nx = make_float4(0.f, 0.f, 0.f, 0.f);
    if (gn < G) nx = *(const float4*)(In + (size_t)gn * 256 + lane * 4);

    float4 v = av;
    v.x = fmaxf(fmaf(fa.x, v.x, fd.x), 0.f);
    v.y = fmaxf(fmaf(fa.y, v.y, fd.y), 0.f);
    v.z = fmaxf(fmaf(fa.z, v.z, fd.z), 0.f);
    v.w = fmaxf(fmaf(fa.w, v.w, fd.w), 0.f);
    const float a4[4] = {v.x, v.y, v.z, v.w};

    float acc0 = bias, acc1 = bias, acc2 = bias, acc3 = bias;
#pragma unroll
    for (int k = 0; k < 64; ++k) {
      const float ak = a4[k & 3];
      const int sl = k >> 2;
      acc0 = fmaf(rdl(ak, sl), w[k], acc0);
      acc1 = fmaf(rdl(ak, 16 + sl), w[k], acc1);
      acc2 = fmaf(rdl(ak, 32 + sl), w[k], acc2);
      acc3 = fmaf(rdl(ak, 48 + sl), w[k], acc3);
    }

    const int r0 = g * 4;
    if (MODE == 1) {
      const float o0 = fmaxf(acc0, 0.f), o1 = fmaxf(acc1, 0.f);
      const float o2 = fmaxf(acc2, 0.f), o3 = fmaxf(acc3, 0.f);
      Out[(size_t)(r0 + 0) * OUTC + lane] = o0;
      Out[(size_t)(r0 + 1) * OUTC + lane] = o1;
      Out[(size_t)(r0 + 2) * OUTC + lane] = o2;
      Out[(size_t)(r0 + 3) * OUTC + lane] = o3;
      sc += o0 + o1 + o2 + o3;
      qc = fmaf(o0, o0, qc);
      qc = fmaf(o1, o1, qc);
      qc = fmaf(o2, o2, qc);
      qc = fmaf(o3, o3, qc);
    } else {  // MODE 3: log_softmax over OUTC cols (lanes >= OUTC masked out)
      float m0 = (lane < OUTC) ? acc0 : -1e30f;
      float m1 = (lane < OUTC) ? acc1 : -1e30f;
      float m2 = (lane < OUTC) ? acc2 : -1e30f;
      float m3 = (lane < OUTC) ? acc3 : -1e30f;
#pragma unroll
      for (int off = 32; off; off >>= 1) {
        m0 = fmaxf(m0, __shfl_xor(m0, off));
        m1 = fmaxf(m1, __shfl_xor(m1, off));
        m2 = fmaxf(m2, __shfl_xor(m2, off));
        m3 = fmaxf(m3, __shfl_xor(m3, off));
      }
      float s0 = (lane < OUTC) ? expf(acc0 - m0) : 0.f;
      float s1 = (lane < OUTC) ? expf(acc1 - m1) : 0.f;
      float s2 = (lane < OUTC) ? expf(acc2 - m2) : 0.f;
      float s3 = (lane < OUTC) ? expf(acc3 - m3) : 0.f;
#pragma unroll
      for (int off = 32; off; off >>= 1) {
        s0 += __shfl_xor(s0, off);
        s1 += __shfl_xor(s1, off);
        s2 += __shfl_xor(s2, off);
        s3 += __shfl_xor(s3, off);
      }
      if (lane < OUTC) {
        Out[(size_t)(r0 + 0) * OUTC + lane] = acc0 - (m0 + logf(s0));
        Out[(size_t)(r0 + 1) * OUTC + lane] = acc1 - (m1 + logf(s1));
        Out[(size_t)(r0 + 2) * OUTC + lane] = acc2 - (m2 + logf(s2));
        Out[(size_t)(r0 + 3) * OUTC + lane] = acc3 - (m3 + logf(s3));
      }
    }
    av = nx;
  }

  if (MODE == 1) {
    P[(size_t)wid * 128 + lane] = sc;
    P[(size_t)wid * 128 + 64 + lane] = qc;
  }
}

extern "C" void kernel_launch(void* const* d_in, const int* in_sizes, int n_in,
                              void* d_out, int out_size, void* d_ws, size_t ws_size,
                              hipStream_t stream) {
  const float* x = (const float*)d_in[0];
  const int* src = (const int*)d_in[1];
  const int* dst = (const int*)d_in[2];
  const float *W1[3], *b1[3], *g[3], *bt[3], *W2[3], *b2[3];
  for (int i = 0; i < 3; ++i) {
    W1[i] = (const float*)d_in[3 + i * 6 + 0];
    b1[i] = (const float*)d_in[3 + i * 6 + 1];
    g[i] = (const float*)d_in[3 + i * 6 + 2];
    bt[i] = (const float*)d_in[3 + i * 6 + 3];
    W2[i] = (const float*)d_in[3 + i * 6 + 4];
    b2[i] = (const float*)d_in[3 + i * 6 + 5];
  }
  const float* bng[2] = {(const float*)d_in[21], (const float*)d_in[23]};
  const float* bnb[2] = {(const float*)d_in[22], (const float*)d_in[24]};

  const int N = NN, E = NE;
  const size_t N64 = (size_t)N * 64;
  const int ggat = N / 4;            // 25000 blocks (1 node per wave)
  const int gmlp = NWAVES / 4;       // 2048 blocks (grid-stride)

  // workspace layout (~89 MB)
  char* p = (char*)d_ws;
  float* B = (float*)p; p += N64 * 4;            // Z buffer (fp32)
  float* C = (float*)p; p += N64 * 4;            // relu(h) buffer (fp32)
  __half* V = (__half*)p; p += N64 * 2;          // v rows (half, 128B/row)
  int* gcnt = (int*)p; p += 256 * 4;             // bucket counters (memset)
  float* aff = (float*)p; p += 192 * 4;          // BN LUT: a[64], d[64], e0[64]
  float* P = (float*)p; p += (size_t)NWAVES * 128 * 4;  // k_mlp per-wave partials (4MB)
  double* PB = (double*)p; p += (size_t)SB * 128 * 8;   // stats partials (256KB)
  int* rowbeg = (int*)p; p += (size_t)N * 4;
  int* rowend = (int*)p; p += (size_t)N * 4;
  unsigned int* binned = (unsigned int*)p; p += (size_t)NBK * CAP * 4;
  int* eidx = (int*)p; p += (size_t)NBK * CAP * 4;

  const double invN = 1.0 / (double)N;

  hipMemsetAsync(gcnt, 0, 256 * 4, stream);

  // ---- CSR build (bucketed counting sort, block-local writes) ----
  k_bin<<<(E + EPB - 1) / EPB, 256, 0, stream>>>(src, dst, gcnt, binned, E);
  k_csr<<<NBK, 512, 0, stream>>>(binned, gcnt, rowbeg, rowend, eidx, N);

  // ---- layer 0:  v0 = x @ W1[0];  Z0[n] = sum v0 + b1[0] ----
  k_vmm<false><<<gmlp, 256, 0, stream>>>(x, nullptr, W1[0], V, N);
  k_gather_h<<<ggat, 256, 0, stream>>>(V, rowbeg, rowend, eidx, (const float*)nullptr, b1[0], B, N);
  k_stat<<<SB, 256, 0, stream>>>(B, N, PB);
  k_red2<<<1, 256, 0, stream>>>(PB, SB, g[0], bt[0], invN, aff, (const float*)nullptr);
  k_mlp<64, 1><<<gmlp, 256, 0, stream>>>(B, aff, W2[0], b2[0], C, P, N);
  k_red1<<<RB, 256, 0, stream>>>(P, NWAVES, PB);
  k_red2<<<1, 256, 0, stream>>>(PB, RB, bng[0], bnb[0], invN, aff, W1[1]);  // outer aff + e0

  // ---- layer 1:  v = C @ diag(a)W1[1];  Z[n] = sum v + cnt*e0 + b1[1] ----
  k_vmm<true><<<gmlp, 256, 0, stream>>>(C, aff, W1[1], V, N);
  k_gather_h<<<ggat, 256, 0, stream>>>(V, rowbeg, rowend, eidx, aff + 128, b1[1], B, N);
  k_stat<<<SB, 256, 0, stream>>>(B, N, PB);
  k_red2<<<1, 256, 0, stream>>>(PB, SB, g[1], bt[1], invN, aff, (const float*)nullptr);
  k_mlp<64, 1><<<gmlp, 256, 0, stream>>>(B, aff, W2[1], b2[1], C, P, N);
  k_red1<<<RB, 256, 0, stream>>>(P, NWAVES, PB);
  k_red2<<<1, 256, 0, stream>>>(PB, RB, bng[1], bnb[1], invN, aff, W1[2]);  // outer aff + e0

  // ---- layer 2 (final: fused log_softmax) ----
  k_vmm<true><<<gmlp, 256, 0, stream>>>(C, aff, W1[2], V, N);
  k_gather_h<<<ggat, 256, 0, stream>>>(V, rowbeg, rowend, eidx, aff + 128, b1[2], B, N);
  k_stat<<<SB, 256, 0, stream>>>(B, N, PB);
  k_red2<<<1, 256, 0, stream>>>(PB, SB, g[2], bt[2], invN, aff, (const float*)nullptr);
  k_mlp<40, 3><<<gmlp, 256, 0, stream>>>(B, aff, W2[2], b2[2], (float*)d_out, nullptr, N);
}

// Round 14
// 566.369 us; speedup vs baseline: 1.0222x; 1.0222x over previous
//
#include <hip/hip_runtime.h>
#include <hip/hip_fp16.h>

#define NN 100000
#define NE 1600000
#define NBK 196       // ceil(100000/512) dst buckets (512 nodes each)
#define CAP 10240     // per-bucket edge capacity
#define EPB 8192      // edges per block in k_bin
#define NWAVES 8192   // wave count for k_vmm/k_mlp (grid-stride, streaming)
#define RB 128        // k_red1 blocks (P partial reduce)
#define SB 256        // k_stat blocks (direct matrix stats)

// ---------------- pass 1: bin edges by dst>>9, packed (src<<9)|dst_local ----------------
__global__ __launch_bounds__(256) void k_bin(const int* __restrict__ src,
                                             const int* __restrict__ dst,
                                             int* __restrict__ gcnt,
                                             unsigned int* __restrict__ binned, int E) {
  __shared__ int bcnt[256];
  const int t = threadIdx.x;
  const int e0 = blockIdx.x * EPB;
  bcnt[t] = 0;
  __syncthreads();
  for (int i = 0; i < EPB; i += 256) {
    int e = e0 + i + t;
    if (e < E) atomicAdd(&bcnt[dst[e] >> 9], 1);
  }
  __syncthreads();
  if (t < NBK) {
    int c = bcnt[t];
    bcnt[t] = c ? atomicAdd(&gcnt[t], c) : 0;
  }
  __syncthreads();
  for (int i = 0; i < EPB; i += 256) {
    int e = e0 + i + t;
    if (e < E) {
      int d = dst[e];
      int b = d >> 9;
      int pos = atomicAdd(&bcnt[b], 1);
      if (pos < CAP) binned[(size_t)b * CAP + pos] = ((unsigned int)src[e] << 9) | (d & 511);
    }
  }
}

// ---------------- pass 2: per-bucket local CSR (block-local writes) ----------------
__global__ __launch_bounds__(512) void k_csr(const unsigned int* __restrict__ binned,
                                             const int* __restrict__ gcnt,
                                             int* __restrict__ rowbeg,
                                             int* __restrict__ rowend,
                                             int* __restrict__ eidx, int N) {
  __shared__ int hist[512];
  __shared__ int cur[512];
  const int t = threadIdx.x;
  const int b = blockIdx.x;
  const size_t base = (size_t)b * CAP;
  int cnt = gcnt[b];
  if (cnt > CAP) cnt = CAP;
  hist[t] = 0;
  __syncthreads();
  for (int e = t; e < cnt; e += 512) atomicAdd(&hist[binned[base + e] & 511], 1);
  __syncthreads();
  const int own = hist[t];
  for (int o = 1; o < 512; o <<= 1) {
    int x = (t >= o) ? hist[t - o] : 0;
    __syncthreads();
    hist[t] += x;
    __syncthreads();
  }
  const int incl = hist[t];
  const int excl = incl - own;
  const int node = b * 512 + t;
  if (node < N) {
    rowbeg[node] = (int)base + excl;
    rowend[node] = (int)base + incl;
  }
  cur[t] = excl;
  __syncthreads();
  for (int e = t; e < cnt; e += 512) {
    unsigned int pk = binned[base + e];
    int pos = atomicAdd(&cur[pk & 511], 1);
    eidx[base + pos] = (int)(pk >> 9);
  }
}

// ------- k_stat: column sum/sumsq of M[N][64] -> PB[SB][128] f64, coalesced + ILP-4 -------
__global__ __launch_bounds__(256) void k_stat(const float* __restrict__ M, int N,
                                              double* __restrict__ PB) {
  const int t = threadIdx.x;
  const int c = t & 63;
  const int rr = t >> 6;  // 0..3
  const int j = blockIdx.x;
  const int STR = SB * 4;  // 1024 rows per sweep
  double s0 = 0, s1 = 0, s2 = 0, s3 = 0, q0 = 0, q1 = 0, q2 = 0, q3 = 0;
  int r = j * 4 + rr;
  for (; r + 3 * STR < N; r += 4 * STR) {
    float v0 = M[(size_t)r * 64 + c];
    float v1 = M[(size_t)(r + STR) * 64 + c];
    float v2 = M[(size_t)(r + 2 * STR) * 64 + c];
    float v3 = M[(size_t)(r + 3 * STR) * 64 + c];
    s0 += v0; q0 = fma((double)v0, (double)v0, q0);
    s1 += v1; q1 = fma((double)v1, (double)v1, q1);
    s2 += v2; q2 = fma((double)v2, (double)v2, q2);
    s3 += v3; q3 = fma((double)v3, (double)v3, q3);
  }
  for (; r < N; r += STR) {
    float v = M[(size_t)r * 64 + c];
    s0 += v; q0 = fma((double)v, (double)v, q0);
  }
  __shared__ double rs[256], rq[256];
  rs[t] = (s0 + s1) + (s2 + s3);
  rq[t] = (q0 + q1) + (q2 + q3);
  __syncthreads();
  if (t < 64)
    PB[(size_t)j * 128 + t] = rs[t] + rs[t + 64] + rs[t + 128] + rs[t + 192];
  else if (t < 128) {
    int c2 = t - 64;
    PB[(size_t)j * 128 + 64 + c2] = rq[c2] + rq[c2 + 64] + rq[c2 + 128] + rq[c2 + 192];
  }
}

// ------- k_red1: P[nblk][128] f32 -> PB[RB][128] f64 (for k_mlp's per-wave partials) -------
__global__ __launch_bounds__(256) void k_red1(const float* __restrict__ P, int nblk,
                                              double* __restrict__ PB) {
  const int t = threadIdx.x;
  const int c = t & 127;
  const int half = t >> 7;  // 0 or 1
  const int j = blockIdx.x;
  const int STR = RB * 2;   // 256 rows per sweep
  double a0 = 0.0, a1 = 0.0, a2 = 0.0, a3 = 0.0;
  int r = j * 2 + half;
  for (; r + 3 * STR < nblk; r += 4 * STR) {
    a0 += (double)P[(size_t)r * 128 + c];
    a1 += (double)P[(size_t)(r + STR) * 128 + c];
    a2 += (double)P[(size_t)(r + 2 * STR) * 128 + c];
    a3 += (double)P[(size_t)(r + 3 * STR) * 128 + c];
  }
  for (; r < nblk; r += STR) a0 += (double)P[(size_t)r * 128 + c];
  double acc = (a0 + a1) + (a2 + a3);
  __shared__ double red[256];
  red[t] = acc;
  __syncthreads();
  if (t < 128) PB[(size_t)j * 128 + t] = red[t] + red[t + 128];
}

// ------- k_red2: finish PB[nrows][128], emit BN affine LUT (+ optional e0 = d@W1n) -------
// aff layout: [0..63]=a, [64..127]=d, [128..191]=e0 (only if W1n != null)
__global__ __launch_bounds__(256) void k_red2(const double* __restrict__ PB, int nrows,
                                              const float* __restrict__ g,
                                              const float* __restrict__ bt,
                                              double invN, float* __restrict__ aff,
                                              const float* __restrict__ W1n) {
  const int t = threadIdx.x;
  const int c = t & 127;
  const int half = t >> 7;
  double a0 = 0.0, a1 = 0.0, a2 = 0.0, a3 = 0.0;
  int j = half;
  for (; j + 6 < nrows; j += 8) {
    a0 += PB[(size_t)j * 128 + c];
    a1 += PB[(size_t)(j + 2) * 128 + c];
    a2 += PB[(size_t)(j + 4) * 128 + c];
    a3 += PB[(size_t)(j + 6) * 128 + c];
  }
  for (; j < nrows; j += 2) a0 += PB[(size_t)j * 128 + c];
  __shared__ double st[256];
  __shared__ float sd[64];
  st[t] = (a0 + a1) + (a2 + a3);
  __syncthreads();
  if (t < 128) st[t] = st[t] + st[t + 128];
  __syncthreads();
  if (t < 64) {
    double mu = st[t] * invN;
    double var = st[64 + t] * invN - mu * mu;
    double ai = (double)g[t] / sqrt(var + 1e-5);
    float dv = (float)((double)bt[t] - ai * mu);
    aff[t] = (float)ai;
    aff[64 + t] = dv;
    sd[t] = dv;
  }
  __syncthreads();
  if (W1n && t < 64) {
    float e = 0.f;
#pragma unroll
    for (int k = 0; k < 64; ++k) e = fmaf(sd[k], W1n[k * 64 + t], e);
    aff[128 + t] = e;
  }
}

__device__ __forceinline__ float rdl(float v, int l) {
  return __int_as_float(__builtin_amdgcn_readlane(__float_as_int(v), l));
}

// ========== k_vmm: v = In @ (diag(a)*W1) -> half  (streaming, coalesced) ==========
// XFORM=true scales W row k by aff[k] (outer-BN a); bias handled in gather epilogue.
template <bool XFORM>
__global__ __launch_bounds__(256) void k_vmm(const float* __restrict__ In,
                                             const float* __restrict__ aff,
                                             const float* __restrict__ W,
                                             __half* __restrict__ Outh, int N) {
  const int lane = threadIdx.x & 63;
  const int wid = (blockIdx.x * 256 + threadIdx.x) >> 6;
  const int nw = NWAVES;
  const int G = N >> 2;

  float w[64];
#pragma unroll
  for (int k = 0; k < 64; ++k) {
    float wk = W[k * 64 + lane];
    if (XFORM) wk *= aff[k];
    w[k] = wk;
  }

  int g = wid;
  float4 av = make_float4(0.f, 0.f, 0.f, 0.f);
  if (g < G) av = *(const float4*)(In + (size_t)g * 256 + lane * 4);
  for (; g < G; g += nw) {
    const int gn = g + nw;
    float4 nx = make_float4(0.f, 0.f, 0.f, 0.f);
    if (gn < G) nx = *(const float4*)(In + (size_t)gn * 256 + lane * 4);

    const float a4[4] = {av.x, av.y, av.z, av.w};
    float acc0 = 0.f, acc1 = 0.f, acc2 = 0.f, acc3 = 0.f;
#pragma unroll
    for (int k = 0; k < 64; ++k) {
      const float ak = a4[k & 3];
      const int sl = k >> 2;
      acc0 = fmaf(rdl(ak, sl), w[k], acc0);
      acc1 = fmaf(rdl(ak, 16 + sl), w[k], acc1);
      acc2 = fmaf(rdl(ak, 32 + sl), w[k], acc2);
      acc3 = fmaf(rdl(ak, 48 + sl), w[k], acc3);
    }
    const int r0 = g * 4;
    Outh[(size_t)(r0 + 0) * 64 + lane] = __float2half(acc0);
    Outh[(size_t)(r0 + 1) * 64 + lane] = __float2half(acc1);
    Outh[(size_t)(r0 + 2) * 64 + lane] = __float2half(acc2);
    Outh[(size_t)(r0 + 3) * 64 + lane] = __float2half(acc3);
    av = nx;
  }
}

// convert+accumulate 8 halfs (one uint4) into two float4 accumulators
__device__ __forceinline__ void h8_acc(const uint4 r, float4& a, float4& b) {
  const float2 f0 = __half22float2(*(const __half2*)&r.x);
  const float2 f1 = __half22float2(*(const __half2*)&r.y);
  const float2 f2 = __half22float2(*(const __half2*)&r.z);
  const float2 f3 = __half22float2(*(const __half2*)&r.w);
  a.x += f0.x; a.y += f0.y; a.z += f1.x; a.w += f1.y;
  b.x += f2.x; b.y += f2.y; b.z += f3.x; b.w += f3.y;
}

// ========== k_gather_h: Z[n] = sum_{n ∪ nb} v[m] + cnt_n*e0 + b1  (half rows, 128B) ==========
// 1 node/wave; 8 edge-groups of 8 lanes, uint4 (16B) per lane covers the 128B row;
// unroll-2 -> 16 outstanding 16B loads per node (vs 8x8B in the round-13 version,
// which was issue-bound). Butterfly over offsets 8/16/32; lanes 0-7 write the row.
__global__ __launch_bounds__(256) void k_gather_h(const __half* __restrict__ V,
                                                  const int* __restrict__ rowbeg,
                                                  const int* __restrict__ rowend,
                                                  const int* __restrict__ eidx,
                                                  const float* __restrict__ e0,
                                                  const float* __restrict__ b1,
                                                  float* __restrict__ Out, int N) {
  const int node = blockIdx.x * 4 + (threadIdx.x >> 6);
  if (node >= N) return;
  const int lane = threadIdx.x & 63;
  const int grp = lane >> 3;   // edge group 0..7
  const int c8 = lane & 7;     // 16B chunk (8 halfs) within the row
  const int beg = rowbeg[node], end = rowend[node];

  float4 sA = make_float4(0.f, 0.f, 0.f, 0.f), sB = sA;
  float4 tA = sA, tB = sA;
  if (grp == 0) {
    const uint4 r = *(const uint4*)(V + (size_t)node * 64 + c8 * 8);  // self (eps=0)
    h8_acc(r, sA, sB);
  }
  int i = beg + grp;
  for (; i + 8 < end; i += 16) {
    const int ea = eidx[i];
    const int eb = eidx[i + 8];
    const uint4 r0 = *(const uint4*)(V + (size_t)ea * 64 + c8 * 8);
    const uint4 r1 = *(const uint4*)(V + (size_t)eb * 64 + c8 * 8);
    h8_acc(r0, sA, sB);
    h8_acc(r1, tA, tB);
  }
  if (i < end) {
    const uint4 r = *(const uint4*)(V + (size_t)eidx[i] * 64 + c8 * 8);
    h8_acc(r, sA, sB);
  }
  sA.x += tA.x; sA.y += tA.y; sA.z += tA.z; sA.w += tA.w;
  sB.x += tB.x; sB.y += tB.y; sB.z += tB.z; sB.w += tB.w;
#pragma unroll
  for (int off = 8; off < 64; off <<= 1) {  // butterfly across the 8 groups
    sA.x += __shfl_xor(sA.x, off);
    sA.y += __shfl_xor(sA.y, off);
    sA.z += __shfl_xor(sA.z, off);
    sA.w += __shfl_xor(sA.w, off);
    sB.x += __shfl_xor(sB.x, off);
    sB.y += __shfl_xor(sB.y, off);
    sB.z += __shfl_xor(sB.z, off);
    sB.w += __shfl_xor(sB.w, off);
  }
  if (grp == 0) {
    float4 oA = *(const float4*)(b1 + c8 * 8);
    float4 oB = *(const float4*)(b1 + c8 * 8 + 4);
    if (e0) {
      const float4 eA = *(const float4*)(e0 + c8 * 8);
      const float4 eB = *(const float4*)(e0 + c8 * 8 + 4);
      const float cnt = (float)(end - beg + 1);
      oA.x = fmaf(cnt, eA.x, oA.x);
      oA.y = fmaf(cnt, eA.y, oA.y);
      oA.z = fmaf(cnt, eA.z, oA.z);
      oA.w = fmaf(cnt, eA.w, oA.w);
      oB.x = fmaf(cnt, eB.x, oB.x);
      oB.y = fmaf(cnt, eB.y, oB.y);
      oB.z = fmaf(cnt, eB.z, oB.z);
      oB.w = fmaf(cnt, eB.w, oB.w);
    }
    oA.x += sA.x; oA.y += sA.y; oA.z += sA.z; oA.w += sA.w;
    oB.x += sB.x; oB.y += sB.y; oB.z += sB.z; oB.w += sB.w;
    *(float4*)(Out + (size_t)node * 64 + c8 * 8) = oA;
    *(float4*)(Out + (size_t)node * 64 + c8 * 8 + 4) = oB;
  }
}

// ========== register-resident GEMM2 (per-wave epilogue, no LDS/barriers) ==========
// MODE 1: relu(out), store, stats(relu)   [inner layers]
// MODE 3: log_softmax(out) -> store        [final layer]
template <int OUTC, int MODE>
__global__ __launch_bounds__(256) void k_mlp(const float* __restrict__ In,
                                             const float* __restrict__ aff,
                                             const float* __restrict__ W,
                                             const float* __restrict__ b,
                                             float* __restrict__ Out,
                                             float* __restrict__ P, int N) {
  const int lane = threadIdx.x & 63;
  const int wid = (blockIdx.x * 256 + threadIdx.x) >> 6;
  const int nw = NWAVES;
  const int G = N >> 2;

  const int cc = (lane < OUTC) ? lane : 0;
  float w[64];
#pragma unroll
  for (int k = 0; k < 64; ++k) w[k] = W[k * OUTC + cc];
  const float bias = b[cc];

  const float4 fa = *(const float4*)(aff + (lane & 15) * 4);
  const float4 fd = *(const float4*)(aff + 64 + (lane & 15) * 4);

  float sc = 0.f, qc = 0.f;

  int g = wid;
  float4 av = make_float4(0.f, 0.f, 0.f, 0.f);
  if (g < G) av = *(const float4*)(In + (size_t)g * 256 + lane * 4);
  for (; g < G; g += nw) {
    const int gn = g + nw;
    float4 nx = make_float4(0.f, 0.f, 0.f, 0.f);
    if (gn < G) nx = *(const float4*)(In + (size_t)gn * 256 + lane * 4);

    float4 v = av;
    v.x = fmaxf(fmaf(fa.x, v.x, fd.x), 0.f);
    v.y = fmaxf(fmaf(fa.y, v.y, fd.y), 0.f);
    v.z = fmaxf(fmaf(fa.z, v.z, fd.z), 0.f);
    v.w = fmaxf(fmaf(fa.w, v.w, fd.w), 0.f);
    const float a4[4] = {v.x, v.y, v.z, v.w};

    float acc0 = bias, acc1 = bias, acc2 = bias, acc3 = bias;
#pragma unroll
    for (int k = 0; k < 64; ++k) {
      const float ak = a4[k & 3];
      const int sl = k >> 2;
      acc0 = fmaf(rdl(ak, sl), w[k], acc0);
      acc1 = fmaf(rdl(ak, 16 + sl), w[k], acc1);
      acc2 = fmaf(rdl(ak, 32 + sl), w[k], acc2);
      acc3 = fmaf(rdl(ak, 48 + sl), w[k], acc3);
    }

    const int r0 = g * 4;
    if (MODE == 1) {
      const float o0 = fmaxf(acc0, 0.f), o1 = fmaxf(acc1, 0.f);
      const float o2 = fmaxf(acc2, 0.f), o3 = fmaxf(acc3, 0.f);
      Out[(size_t)(r0 + 0) * OUTC + lane] = o0;
      Out[(size_t)(r0 + 1) * OUTC + lane] = o1;
      Out[(size_t)(r0 + 2) * OUTC + lane] = o2;
      Out[(size_t)(r0 + 3) * OUTC + lane] = o3;
      sc += o0 + o1 + o2 + o3;
      qc = fmaf(o0, o0, qc);
      qc = fmaf(o1, o1, qc);
      qc = fmaf(o2, o2, qc);
      qc = fmaf(o3, o3, qc);
    } else {  // MODE 3: log_softmax over OUTC cols (lanes >= OUTC masked out)
      float m0 = (lane < OUTC) ? acc0 : -1e30f;
      float m1 = (lane < OUTC) ? acc1 : -1e30f;
      float m2 = (lane < OUTC) ? acc2 : -1e30f;
      float m3 = (lane < OUTC) ? acc3 : -1e30f;
#pragma unroll
      for (int off = 32; off; off >>= 1) {
        m0 = fmaxf(m0, __shfl_xor(m0, off));
        m1 = fmaxf(m1, __shfl_xor(m1, off));
        m2 = fmaxf(m2, __shfl_xor(m2, off));
        m3 = fmaxf(m3, __shfl_xor(m3, off));
      }
      float s0 = (lane < OUTC) ? expf(acc0 - m0) : 0.f;
      float s1 = (lane < OUTC) ? expf(acc1 - m1) : 0.f;
      float s2 = (lane < OUTC) ? expf(acc2 - m2) : 0.f;
      float s3 = (lane < OUTC) ? expf(acc3 - m3) : 0.f;
#pragma unroll
      for (int off = 32; off; off >>= 1) {
        s0 += __shfl_xor(s0, off);
        s1 += __shfl_xor(s1, off);
        s2 += __shfl_xor(s2, off);
        s3 += __shfl_xor(s3, off);
      }
      if (lane < OUTC) {
        Out[(size_t)(r0 + 0) * OUTC + lane] = acc0 - (m0 + logf(s0));
        Out[(size_t)(r0 + 1) * OUTC + lane] = acc1 - (m1 + logf(s1));
        Out[(size_t)(r0 + 2) * OUTC + lane] = acc2 - (m2 + logf(s2));
        Out[(size_t)(r0 + 3) * OUTC + lane] = acc3 - (m3 + logf(s3));
      }
    }
    av = nx;
  }

  if (MODE == 1) {
    P[(size_t)wid * 128 + lane] = sc;
    P[(size_t)wid * 128 + 64 + lane] = qc;
  }
}

extern "C" void kernel_launch(void* const* d_in, const int* in_sizes, int n_in,
                              void* d_out, int out_size, void* d_ws, size_t ws_size,
                              hipStream_t stream) {
  const float* x = (const float*)d_in[0];
  const int* src = (const int*)d_in[1];
  const int* dst = (const int*)d_in[2];
  const float *W1[3], *b1[3], *g[3], *bt[3], *W2[3], *b2[3];
  for (int i = 0; i < 3; ++i) {
    W1[i] = (const float*)d_in[3 + i * 6 + 0];
    b1[i] = (const float*)d_in[3 + i * 6 + 1];
    g[i] = (const float*)d_in[3 + i * 6 + 2];
    bt[i] = (const float*)d_in[3 + i * 6 + 3];
    W2[i] = (const float*)d_in[3 + i * 6 + 4];
    b2[i] = (const float*)d_in[3 + i * 6 + 5];
  }
  const float* bng[2] = {(const float*)d_in[21], (const float*)d_in[23]};
  const float* bnb[2] = {(const float*)d_in[22], (const float*)d_in[24]};

  const int N = NN, E = NE;
  const size_t N64 = (size_t)N * 64;
  const int ggat = N / 4;            // 25000 blocks (1 node per wave)
  const int gmlp = NWAVES / 4;       // 2048 blocks (grid-stride)

  // workspace layout (~89 MB)
  char* p = (char*)d_ws;
  float* B = (float*)p; p += N64 * 4;            // Z buffer (fp32)
  float* C = (float*)p; p += N64 * 4;            // relu(h) buffer (fp32)
  __half* V = (__half*)p; p += N64 * 2;          // v rows (half, 128B/row)
  int* gcnt = (int*)p; p += 256 * 4;             // bucket counters (memset)
  float* aff = (float*)p; p += 192 * 4;          // BN LUT: a[64], d[64], e0[64]
  float* P = (float*)p; p += (size_t)NWAVES * 128 * 4;  // k_mlp per-wave partials (4MB)
  double* PB = (double*)p; p += (size_t)SB * 128 * 8;   // stats partials (256KB)
  int* rowbeg = (int*)p; p += (size_t)N * 4;
  int* rowend = (int*)p; p += (size_t)N * 4;
  unsigned int* binned = (unsigned int*)p; p += (size_t)NBK * CAP * 4;
  int* eidx = (int*)p; p += (size_t)NBK * CAP * 4;

  const double invN = 1.0 / (double)N;

  hipMemsetAsync(gcnt, 0, 256 * 4, stream);

  // ---- CSR build (bucketed counting sort, block-local writes) ----
  k_bin<<<(E + EPB - 1) / EPB, 256, 0, stream>>>(src, dst, gcnt, binned, E);
  k_csr<<<NBK, 512, 0, stream>>>(binned, gcnt, rowbeg, rowend, eidx, N);

  // ---- layer 0:  v0 = x @ W1[0];  Z0[n] = sum v0 + b1[0] ----
  k_vmm<false><<<gmlp, 256, 0, stream>>>(x, nullptr, W1[0], V, N);
  k_gather_h<<<ggat, 256, 0, stream>>>(V, rowbeg, rowend, eidx, (const float*)nullptr, b1[0], B, N);
  k_stat<<<SB, 256, 0, stream>>>(B, N, PB);
  k_red2<<<1, 256, 0, stream>>>(PB, SB, g[0], bt[0], invN, aff, (const float*)nullptr);
  k_mlp<64, 1><<<gmlp, 256, 0, stream>>>(B, aff, W2[0], b2[0], C, P, N);
  k_red1<<<RB, 256, 0, stream>>>(P, NWAVES, PB);
  k_red2<<<1, 256, 0, stream>>>(PB, RB, bng[0], bnb[0], invN, aff, W1[1]);  // outer aff + e0

  // ---- layer 1:  v = C @ diag(a)W1[1];  Z[n] = sum v + cnt*e0 + b1[1] ----
  k_vmm<true><<<gmlp, 256, 0, stream>>>(C, aff, W1[1], V, N);
  k_gather_h<<<ggat, 256, 0, stream>>>(V, rowbeg, rowend, eidx, aff + 128, b1[1], B, N);
  k_stat<<<SB, 256, 0, stream>>>(B, N, PB);
  k_red2<<<1, 256, 0, stream>>>(PB, SB, g[1], bt[1], invN, aff, (const float*)nullptr);
  k_mlp<64, 1><<<gmlp, 256, 0, stream>>>(B, aff, W2[1], b2[1], C, P, N);
  k_red1<<<RB, 256, 0, stream>>>(P, NWAVES, PB);
  k_red2<<<1, 256, 0, stream>>>(PB, RB, bng[1], bnb[1], invN, aff, W1[2]);  // outer aff + e0

  // ---- layer 2 (final: fused log_softmax) ----
  k_vmm<true><<<gmlp, 256, 0, stream>>>(C, aff, W1[2], V, N);
  k_gather_h<<<ggat, 256, 0, stream>>>(V, rowbeg, rowend, eidx, aff + 128, b1[2], B, N);
  k_stat<<<SB, 256, 0, stream>>>(B, N, PB);
  k_red2<<<1, 256, 0, stream>>>(PB, SB, g[2], bt[2], invN, aff, (const float*)nullptr);
  k_mlp<40, 3><<<gmlp, 256, 0, stream>>>(B, aff, W2[2], b2[2], (float*)d_out, nullptr, N);
}

// Round 15
// 557.914 us; speedup vs baseline: 1.0377x; 1.0152x over previous
//
#include <hip/hip_runtime.h>
#include <hip/hip_fp16.h>

#define NN 100000
#define NE 1600000
#define NBK 196       // ceil(100000/512) dst buckets (512 nodes each)
#define CAP 10240     // per-bucket edge capacity
#define EPB 4096      // edges per block in k_bin (391 blocks -> >1 block/CU)
#define NWAVES 8192   // wave count for k_vmm/k_mlp (grid-stride, streaming)
#define RB 128        // k_red1 blocks (P partial reduce)
#define SB 256        // k_stat blocks (direct matrix stats)

// ---------------- pass 1: bin edges by dst>>9, packed (src<<9)|dst_local ----------------
__global__ __launch_bounds__(256) void k_bin(const int* __restrict__ src,
                                             const int* __restrict__ dst,
                                             int* __restrict__ gcnt,
                                             unsigned int* __restrict__ binned, int E) {
  __shared__ int bcnt[256];
  const int t = threadIdx.x;
  const int e0 = blockIdx.x * EPB;
  bcnt[t] = 0;
  __syncthreads();
  for (int i = 0; i < EPB; i += 256) {
    int e = e0 + i + t;
    if (e < E) atomicAdd(&bcnt[dst[e] >> 9], 1);
  }
  __syncthreads();
  if (t < NBK) {
    int c = bcnt[t];
    bcnt[t] = c ? atomicAdd(&gcnt[t], c) : 0;
  }
  __syncthreads();
  for (int i = 0; i < EPB; i += 256) {
    int e = e0 + i + t;
    if (e < E) {
      int d = dst[e];
      int b = d >> 9;
      int pos = atomicAdd(&bcnt[b], 1);
      if (pos < CAP) binned[(size_t)b * CAP + pos] = ((unsigned int)src[e] << 9) | (d & 511);
    }
  }
}

// ---------------- pass 2: per-bucket local CSR (block-local writes) ----------------
__global__ __launch_bounds__(512) void k_csr(const unsigned int* __restrict__ binned,
                                             const int* __restrict__ gcnt,
                                             int* __restrict__ rowbeg,
                                             int* __restrict__ rowend,
                                             int* __restrict__ eidx, int N) {
  __shared__ int hist[512];
  __shared__ int cur[512];
  const int t = threadIdx.x;
  const int b = blockIdx.x;
  const size_t base = (size_t)b * CAP;
  int cnt = gcnt[b];
  if (cnt > CAP) cnt = CAP;
  hist[t] = 0;
  __syncthreads();
  for (int e = t; e < cnt; e += 512) atomicAdd(&hist[binned[base + e] & 511], 1);
  __syncthreads();
  const int own = hist[t];
  for (int o = 1; o < 512; o <<= 1) {
    int x = (t >= o) ? hist[t - o] : 0;
    __syncthreads();
    hist[t] += x;
    __syncthreads();
  }
  const int incl = hist[t];
  const int excl = incl - own;
  const int node = b * 512 + t;
  if (node < N) {
    rowbeg[node] = (int)base + excl;
    rowend[node] = (int)base + incl;
  }
  cur[t] = excl;
  __syncthreads();
  for (int e = t; e < cnt; e += 512) {
    unsigned int pk = binned[base + e];
    int pos = atomicAdd(&cur[pk & 511], 1);
    eidx[base + pos] = (int)(pk >> 9);
  }
}

// ------- k_stat: column sum/sumsq of M[N][64] -> PB[SB][128] f64, coalesced + ILP-4 -------
__global__ __launch_bounds__(256) void k_stat(const float* __restrict__ M, int N,
                                              double* __restrict__ PB) {
  const int t = threadIdx.x;
  const int c = t & 63;
  const int rr = t >> 6;  // 0..3
  const int j = blockIdx.x;
  const int STR = SB * 4;  // 1024 rows per sweep
  double s0 = 0, s1 = 0, s2 = 0, s3 = 0, q0 = 0, q1 = 0, q2 = 0, q3 = 0;
  int r = j * 4 + rr;
  for (; r + 3 * STR < N; r += 4 * STR) {
    float v0 = M[(size_t)r * 64 + c];
    float v1 = M[(size_t)(r + STR) * 64 + c];
    float v2 = M[(size_t)(r + 2 * STR) * 64 + c];
    float v3 = M[(size_t)(r + 3 * STR) * 64 + c];
    s0 += v0; q0 = fma((double)v0, (double)v0, q0);
    s1 += v1; q1 = fma((double)v1, (double)v1, q1);
    s2 += v2; q2 = fma((double)v2, (double)v2, q2);
    s3 += v3; q3 = fma((double)v3, (double)v3, q3);
  }
  for (; r < N; r += STR) {
    float v = M[(size_t)r * 64 + c];
    s0 += v; q0 = fma((double)v, (double)v, q0);
  }
  __shared__ double rs[256], rq[256];
  rs[t] = (s0 + s1) + (s2 + s3);
  rq[t] = (q0 + q1) + (q2 + q3);
  __syncthreads();
  if (t < 64)
    PB[(size_t)j * 128 + t] = rs[t] + rs[t + 64] + rs[t + 128] + rs[t + 192];
  else if (t < 128) {
    int c2 = t - 64;
    PB[(size_t)j * 128 + 64 + c2] = rq[c2] + rq[c2 + 64] + rq[c2 + 128] + rq[c2 + 192];
  }
}

// ------- k_red1: P[nblk][128] f32 -> PB[RB][128] f64 (for k_mlp's per-wave partials) -------
__global__ __launch_bounds__(256) void k_red1(const float* __restrict__ P, int nblk,
                                              double* __restrict__ PB) {
  const int t = threadIdx.x;
  const int c = t & 127;
  const int half = t >> 7;  // 0 or 1
  const int j = blockIdx.x;
  const int STR = RB * 2;   // 256 rows per sweep
  double a0 = 0.0, a1 = 0.0, a2 = 0.0, a3 = 0.0;
  int r = j * 2 + half;
  for (; r + 3 * STR < nblk; r += 4 * STR) {
    a0 += (double)P[(size_t)r * 128 + c];
    a1 += (double)P[(size_t)(r + STR) * 128 + c];
    a2 += (double)P[(size_t)(r + 2 * STR) * 128 + c];
    a3 += (double)P[(size_t)(r + 3 * STR) * 128 + c];
  }
  for (; r < nblk; r += STR) a0 += (double)P[(size_t)r * 128 + c];
  double acc = (a0 + a1) + (a2 + a3);
  __shared__ double red[256];
  red[t] = acc;
  __syncthreads();
  if (t < 128) PB[(size_t)j * 128 + t] = red[t] + red[t + 128];
}

// ------- k_red2: finish PB[nrows][128], emit BN affine LUT (+ optional e0 = d@W1n) -------
// aff layout: [0..63]=a, [64..127]=d, [128..191]=e0 (only if W1n != null)
__global__ __launch_bounds__(256) void k_red2(const double* __restrict__ PB, int nrows,
                                              const float* __restrict__ g,
                                              const float* __restrict__ bt,
                                              double invN, float* __restrict__ aff,
                                              const float* __restrict__ W1n) {
  const int t = threadIdx.x;
  const int c = t & 127;
  const int half = t >> 7;
  double a0 = 0.0, a1 = 0.0, a2 = 0.0, a3 = 0.0;
  int j = half;
  for (; j + 6 < nrows; j += 8) {
    a0 += PB[(size_t)j * 128 + c];
    a1 += PB[(size_t)(j + 2) * 128 + c];
    a2 += PB[(size_t)(j + 4) * 128 + c];
    a3 += PB[(size_t)(j + 6) * 128 + c];
  }
  for (; j < nrows; j += 2) a0 += PB[(size_t)j * 128 + c];
  __shared__ double st[256];
  __shared__ float sd[64];
  st[t] = (a0 + a1) + (a2 + a3);
  __syncthreads();
  if (t < 128) st[t] = st[t] + st[t + 128];
  __syncthreads();
  if (t < 64) {
    double mu = st[t] * invN;
    double var = st[64 + t] * invN - mu * mu;
    double ai = (double)g[t] / sqrt(var + 1e-5);
    float dv = (float)((double)bt[t] - ai * mu);
    aff[t] = (float)ai;
    aff[64 + t] = dv;
    sd[t] = dv;
  }
  __syncthreads();
  if (W1n && t < 64) {
    float e = 0.f;
#pragma unroll
    for (int k = 0; k < 64; ++k) e = fmaf(sd[k], W1n[k * 64 + t], e);
    aff[128 + t] = e;
  }
}

__device__ __forceinline__ float rdl(float v, int l) {
  return __int_as_float(__builtin_amdgcn_readlane(__float_as_int(v), l));
}

// ========== k_vmm: v = In @ (diag(a)*W1) -> half  (streaming, coalesced) ==========
// XFORM=true scales W row k by aff[k] (outer-BN a); bias handled in gather epilogue.
template <bool XFORM>
__global__ __launch_bounds__(256) void k_vmm(const float* __restrict__ In,
                                             const float* __restrict__ aff,
                                             const float* __restrict__ W,
                                             __half* __restrict__ Outh, int N) {
  const int lane = threadIdx.x & 63;
  const int wid = (blockIdx.x * 256 + threadIdx.x) >> 6;
  const int nw = NWAVES;
  const int G = N >> 2;

  float w[64];
#pragma unroll
  for (int k = 0; k < 64; ++k) {
    float wk = W[k * 64 + lane];
    if (XFORM) wk *= aff[k];
    w[k] = wk;
  }

  int g = wid;
  float4 av = make_float4(0.f, 0.f, 0.f, 0.f);
  if (g < G) av = *(const float4*)(In + (size_t)g * 256 + lane * 4);
  for (; g < G; g += nw) {
    const int gn = g + nw;
    float4 nx = make_float4(0.f, 0.f, 0.f, 0.f);
    if (gn < G) nx = *(const float4*)(In + (size_t)gn * 256 + lane * 4);

    const float a4[4] = {av.x, av.y, av.z, av.w};
    float acc0 = 0.f, acc1 = 0.f, acc2 = 0.f, acc3 = 0.f;
#pragma unroll
    for (int k = 0; k < 64; ++k) {
      const float ak = a4[k & 3];
      const int sl = k >> 2;
      acc0 = fmaf(rdl(ak, sl), w[k], acc0);
      acc1 = fmaf(rdl(ak, 16 + sl), w[k], acc1);
      acc2 = fmaf(rdl(ak, 32 + sl), w[k], acc2);
      acc3 = fmaf(rdl(ak, 48 + sl), w[k], acc3);
    }
    const int r0 = g * 4;
    Outh[(size_t)(r0 + 0) * 64 + lane] = __float2half(acc0);
    Outh[(size_t)(r0 + 1) * 64 + lane] = __float2half(acc1);
    Outh[(size_t)(r0 + 2) * 64 + lane] = __float2half(acc2);
    Outh[(size_t)(r0 + 3) * 64 + lane] = __float2half(acc3);
    av = nx;
  }
}

// convert+accumulate 8 halfs (one uint4) into two float4 accumulators
__device__ __forceinline__ void h8_acc(const uint4 r, float4& a, float4& b) {
  const float2 f0 = __half22float2(*(const __half2*)&r.x);
  const float2 f1 = __half22float2(*(const __half2*)&r.y);
  const float2 f2 = __half22float2(*(const __half2*)&r.z);
  const float2 f3 = __half22float2(*(const __half2*)&r.w);
  a.x += f0.x; a.y += f0.y; a.z += f1.x; a.w += f1.y;
  b.x += f2.x; b.y += f2.y; b.z += f3.x; b.w += f3.y;
}

// pair two uint4 half-rows with packed half adds (4x v_pk_add_f16), then convert once
__device__ __forceinline__ uint4 h8_pair(const uint4 r0, const uint4 r1) {
  uint4 o;
  *(__half2*)&o.x = __hadd2(*(const __half2*)&r0.x, *(const __half2*)&r1.x);
  *(__half2*)&o.y = __hadd2(*(const __half2*)&r0.y, *(const __half2*)&r1.y);
  *(__half2*)&o.z = __hadd2(*(const __half2*)&r0.z, *(const __half2*)&r1.z);
  *(__half2*)&o.w = __hadd2(*(const __half2*)&r0.w, *(const __half2*)&r1.w);
  return o;
}

// ========== k_gather_h: Z[n] = sum_{n ∪ nb} v[m] + cnt_n*e0 + b1  (half rows, 128B) ==========
// 1 node/wave; 8 edge-groups of 8 lanes, uint4 (16B) per lane covers the 128B row;
// unroll-2 with v_pk_add_f16 pairing: 4 pk + 8 cvt + 8 add per 2 edges (was 16+16).
// Butterfly over offsets 8/16/32; lanes 0-7 write the row.
__global__ __launch_bounds__(256) void k_gather_h(const __half* __restrict__ V,
                                                  const int* __restrict__ rowbeg,
                                                  const int* __restrict__ rowend,
                                                  const int* __restrict__ eidx,
                                                  const float* __restrict__ e0,
                                                  const float* __restrict__ b1,
                                                  float* __restrict__ Out, int N) {
  const int node = blockIdx.x * 4 + (threadIdx.x >> 6);
  if (node >= N) return;
  const int lane = threadIdx.x & 63;
  const int grp = lane >> 3;   // edge group 0..7
  const int c8 = lane & 7;     // 16B chunk (8 halfs) within the row
  const int beg = rowbeg[node], end = rowend[node];

  float4 sA = make_float4(0.f, 0.f, 0.f, 0.f), sB = sA;
  if (grp == 0) {
    const uint4 r = *(const uint4*)(V + (size_t)node * 64 + c8 * 8);  // self (eps=0)
    h8_acc(r, sA, sB);
  }
  int i = beg + grp;
  for (; i + 8 < end; i += 16) {
    const int ea = eidx[i];
    const int eb = eidx[i + 8];
    const uint4 r0 = *(const uint4*)(V + (size_t)ea * 64 + c8 * 8);
    const uint4 r1 = *(const uint4*)(V + (size_t)eb * 64 + c8 * 8);
    h8_acc(h8_pair(r0, r1), sA, sB);  // one half-precision rounding per pair (~2^-11)
  }
  if (i < end) {
    const uint4 r = *(const uint4*)(V + (size_t)eidx[i] * 64 + c8 * 8);
    h8_acc(r, sA, sB);
  }
#pragma unroll
  for (int off = 8; off < 64; off <<= 1) {  // butterfly across the 8 groups
    sA.x += __shfl_xor(sA.x, off);
    sA.y += __shfl_xor(sA.y, off);
    sA.z += __shfl_xor(sA.z, off);
    sA.w += __shfl_xor(sA.w, off);
    sB.x += __shfl_xor(sB.x, off);
    sB.y += __shfl_xor(sB.y, off);
    sB.z += __shfl_xor(sB.z, off);
    sB.w += __shfl_xor(sB.w, off);
  }
  if (grp == 0) {
    float4 oA = *(const float4*)(b1 + c8 * 8);
    float4 oB = *(const float4*)(b1 + c8 * 8 + 4);
    if (e0) {
      const float4 eA = *(const float4*)(e0 + c8 * 8);
      const float4 eB = *(const float4*)(e0 + c8 * 8 + 4);
      const float cnt = (float)(end - beg + 1);
      oA.x = fmaf(cnt, eA.x, oA.x);
      oA.y = fmaf(cnt, eA.y, oA.y);
      oA.z = fmaf(cnt, eA.z, oA.z);
      oA.w = fmaf(cnt, eA.w, oA.w);
      oB.x = fmaf(cnt, eB.x, oB.x);
      oB.y = fmaf(cnt, eB.y, oB.y);
      oB.z = fmaf(cnt, eB.z, oB.z);
      oB.w = fmaf(cnt, eB.w, oB.w);
    }
    oA.x += sA.x; oA.y += sA.y; oA.z += sA.z; oA.w += sA.w;
    oB.x += sB.x; oB.y += sB.y; oB.z += sB.z; oB.w += sB.w;
    *(float4*)(Out + (size_t)node * 64 + c8 * 8) = oA;
    *(float4*)(Out + (size_t)node * 64 + c8 * 8 + 4) = oB;
  }
}

// ========== register-resident GEMM2 (per-wave epilogue, no LDS/barriers) ==========
// MODE 1: relu(out), store, stats(relu)   [inner layers]
// MODE 3: log_softmax(out) -> store        [final layer]
template <int OUTC, int MODE>
__global__ __launch_bounds__(256) void k_mlp(const float* __restrict__ In,
                                             const float* __restrict__ aff,
                                             const float* __restrict__ W,
                                             const float* __restrict__ b,
                                             float* __restrict__ Out,
                                             float* __restrict__ P, int N) {
  const int lane = threadIdx.x & 63;
  const int wid = (blockIdx.x * 256 + threadIdx.x) >> 6;
  const int nw = NWAVES;
  const int G = N >> 2;

  const int cc = (lane < OUTC) ? lane : 0;
  float w[64];
#pragma unroll
  for (int k = 0; k < 64; ++k) w[k] = W[k * OUTC + cc];
  const float bias = b[cc];

  const float4 fa = *(const float4*)(aff + (lane & 15) * 4);
  const float4 fd = *(const float4*)(aff + 64 + (lane & 15) * 4);

  float sc = 0.f, qc = 0.f;

  int g = wid;
  float4 av = make_float4(0.f, 0.f, 0.f, 0.f);
  if (g < G) av = *(const float4*)(In + (size_t)g * 256 + lane * 4);
  for (; g < G; g += nw) {
    const int gn = g + nw;
    float4 nx = make_float4(0.f, 0.f, 0.f, 0.f);
    if (gn < G) nx = *(const float4*)(In + (size_t)gn * 256 + lane * 4);

    float4 v = av;
    v.x = fmaxf(fmaf(fa.x, v.x, fd.x), 0.f);
    v.y = fmaxf(fmaf(fa.y, v.y, fd.y), 0.f);
    v.z = fmaxf(fmaf(fa.z, v.z, fd.z), 0.f);
    v.w = fmaxf(fmaf(fa.w, v.w, fd.w), 0.f);
    const float a4[4] = {v.x, v.y, v.z, v.w};

    float acc0 = bias, acc1 = bias, acc2 = bias, acc3 = bias;
#pragma unroll
    for (int k = 0; k < 64; ++k) {
      const float ak = a4[k & 3];
      const int sl = k >> 2;
      acc0 = fmaf(rdl(ak, sl), w[k], acc0);
      acc1 = fmaf(rdl(ak, 16 + sl), w[k], acc1);
      acc2 = fmaf(rdl(ak, 32 + sl), w[k], acc2);
      acc3 = fmaf(rdl(ak, 48 + sl), w[k], acc3);
    }

    const int r0 = g * 4;
    if (MODE == 1) {
      const float o0 = fmaxf(acc0, 0.f), o1 = fmaxf(acc1, 0.f);
      const float o2 = fmaxf(acc2, 0.f), o3 = fmaxf(acc3, 0.f);
      Out[(size_t)(r0 + 0) * OUTC + lane] = o0;
      Out[(size_t)(r0 + 1) * OUTC + lane] = o1;
      Out[(size_t)(r0 + 2) * OUTC + lane] = o2;
      Out[(size_t)(r0 + 3) * OUTC + lane] = o3;
      sc += o0 + o1 + o2 + o3;
      qc = fmaf(o0, o0, qc);
      qc = fmaf(o1, o1, qc);
      qc = fmaf(o2, o2, qc);
      qc = fmaf(o3, o3, qc);
    } else {  // MODE 3: log_softmax over OUTC cols (lanes >= OUTC masked out)
      float m0 = (lane < OUTC) ? acc0 : -1e30f;
      float m1 = (lane < OUTC) ? acc1 : -1e30f;
      float m2 = (lane < OUTC) ? acc2 : -1e30f;
      float m3 = (lane < OUTC) ? acc3 : -1e30f;
#pragma unroll
      for (int off = 32; off; off >>= 1) {
        m0 = fmaxf(m0, __shfl_xor(m0, off));
        m1 = fmaxf(m1, __shfl_xor(m1, off));
        m2 = fmaxf(m2, __shfl_xor(m2, off));
        m3 = fmaxf(m3, __shfl_xor(m3, off));
      }
      float s0 = (lane < OUTC) ? expf(acc0 - m0) : 0.f;
      float s1 = (lane < OUTC) ? expf(acc1 - m1) : 0.f;
      float s2 = (lane < OUTC) ? expf(acc2 - m2) : 0.f;
      float s3 = (lane < OUTC) ? expf(acc3 - m3) : 0.f;
#pragma unroll
      for (int off = 32; off; off >>= 1) {
        s0 += __shfl_xor(s0, off);
        s1 += __shfl_xor(s1, off);
        s2 += __shfl_xor(s2, off);
        s3 += __shfl_xor(s3, off);
      }
      if (lane < OUTC) {
        Out[(size_t)(r0 + 0) * OUTC + lane] = acc0 - (m0 + logf(s0));
        Out[(size_t)(r0 + 1) * OUTC + lane] = acc1 - (m1 + logf(s1));
        Out[(size_t)(r0 + 2) * OUTC + lane] = acc2 - (m2 + logf(s2));
        Out[(size_t)(r0 + 3) * OUTC + lane] = acc3 - (m3 + logf(s3));
      }
    }
    av = nx;
  }

  if (MODE == 1) {
    P[(size_t)wid * 128 + lane] = sc;
    P[(size_t)wid * 128 + 64 + lane] = qc;
  }
}

extern "C" void kernel_launch(void* const* d_in, const int* in_sizes, int n_in,
                              void* d_out, int out_size, void* d_ws, size_t ws_size,
                              hipStream_t stream) {
  const float* x = (const float*)d_in[0];
  const int* src = (const int*)d_in[1];
  const int* dst = (const int*)d_in[2];
  const float *W1[3], *b1[3], *g[3], *bt[3], *W2[3], *b2[3];
  for (int i = 0; i < 3; ++i) {
    W1[i] = (const float*)d_in[3 + i * 6 + 0];
    b1[i] = (const float*)d_in[3 + i * 6 + 1];
    g[i] = (const float*)d_in[3 + i * 6 + 2];
    bt[i] = (const float*)d_in[3 + i * 6 + 3];
    W2[i] = (const float*)d_in[3 + i * 6 + 4];
    b2[i] = (const float*)d_in[3 + i * 6 + 5];
  }
  const float* bng[2] = {(const float*)d_in[21], (const float*)d_in[23]};
  const float* bnb[2] = {(const float*)d_in[22], (const float*)d_in[24]};

  const int N = NN, E = NE;
  const size_t N64 = (size_t)N * 64;
  const int ggat = N / 4;            // 25000 blocks (1 node per wave)
  const int gmlp = NWAVES / 4;       // 2048 blocks (grid-stride)

  // workspace layout (~89 MB)
  char* p = (char*)d_ws;
  float* B = (float*)p; p += N64 * 4;            // Z buffer (fp32)
  float* C = (float*)p; p += N64 * 4;            // relu(h) buffer (fp32)
  __half* V = (__half*)p; p += N64 * 2;          // v rows (half, 128B/row)
  int* gcnt = (int*)p; p += 256 * 4;             // bucket counters (memset)
  float* aff = (float*)p; p += 192 * 4;          // BN LUT: a[64], d[64], e0[64]
  float* P = (float*)p; p += (size_t)NWAVES * 128 * 4;  // k_mlp per-wave partials (4MB)
  double* PB = (double*)p; p += (size_t)SB * 128 * 8;   // stats partials (256KB)
  int* rowbeg = (int*)p; p += (size_t)N * 4;
  int* rowend = (int*)p; p += (size_t)N * 4;
  unsigned int* binned = (unsigned int*)p; p += (size_t)NBK * CAP * 4;
  int* eidx = (int*)p; p += (size_t)NBK * CAP * 4;

  const double invN = 1.0 / (double)N;

  hipMemsetAsync(gcnt, 0, 256 * 4, stream);

  // ---- CSR build (bucketed counting sort, block-local writes) ----
  k_bin<<<(E + EPB - 1) / EPB, 256, 0, stream>>>(src, dst, gcnt, binned, E);
  k_csr<<<NBK, 512, 0, stream>>>(binned, gcnt, rowbeg, rowend, eidx, N);

  // ---- layer 0:  v0 = x @ W1[0];  Z0[n] = sum v0 + b1[0] ----
  k_vmm<false><<<gmlp, 256, 0, stream>>>(x, nullptr, W1[0], V, N);
  k_gather_h<<<ggat, 256, 0, stream>>>(V, rowbeg, rowend, eidx, (const float*)nullptr, b1[0], B, N);
  k_stat<<<SB, 256, 0, stream>>>(B, N, PB);
  k_red2<<<1, 256, 0, stream>>>(PB, SB, g[0], bt[0], invN, aff, (const float*)nullptr);
  k_mlp<64, 1><<<gmlp, 256, 0, stream>>>(B, aff, W2[0], b2[0], C, P, N);
  k_red1<<<RB, 256, 0, stream>>>(P, NWAVES, PB);
  k_red2<<<1, 256, 0, stream>>>(PB, RB, bng[0], bnb[0], invN, aff, W1[1]);  // outer aff + e0

  // ---- layer 1:  v = C @ diag(a)W1[1];  Z[n] = sum v + cnt*e0 + b1[1] ----
  k_vmm<true><<<gmlp, 256, 0, stream>>>(C, aff, W1[1], V, N);
  k_gather_h<<<ggat, 256, 0, stream>>>(V, rowbeg, rowend, eidx, aff + 128, b1[1], B, N);
  k_stat<<<SB, 256, 0, stream>>>(B, N, PB);
  k_red2<<<1, 256, 0, stream>>>(PB, SB, g[1], bt[1], invN, aff, (const float*)nullptr);
  k_mlp<64, 1><<<gmlp, 256, 0, stream>>>(B, aff, W2[1], b2[1], C, P, N);
  k_red1<<<RB, 256, 0, stream>>>(P, NWAVES, PB);
  k_red2<<<1, 256, 0, stream>>>(PB, RB, bng[1], bnb[1], invN, aff, W1[2]);  // outer aff + e0

  // ---- layer 2 (final: fused log_softmax) ----
  k_vmm<true><<<gmlp, 256, 0, stream>>>(C, aff, W1[2], V, N);
  k_gather_h<<<ggat, 256, 0, stream>>>(V, rowbeg, rowend, eidx, aff + 128, b1[2], B, N);
  k_stat<<<SB, 256, 0, stream>>>(B, N, PB);
  k_red2<<<1, 256, 0, stream>>>(PB, SB, g[2], bt[2], invN, aff, (const float*)nullptr);
  k_mlp<40, 3><<<gmlp, 256, 0, stream>>>(B, aff, W2[2], b2[2], (float*)d_out, nullptr, N);
}

// Round 17
// 483.080 us; speedup vs baseline: 1.1985x; 1.1549x over previous
//
#include <hip/hip_runtime.h>
#include <hip/hip_fp16.h>

#define NN 100000
#define NE 1600000
#define NBK 196       // ceil(100000/512) dst buckets (512 nodes each)
#define CAP 10240     // per-bucket edge capacity
#define EPB 4096      // edges per block in k_bin
#define NWAVES 8192   // wave count for k_mlp MODE3 (grid-stride)
#define RB 128        // k_red1 blocks (P partial reduce)
#define SB 256        // k_stat blocks (direct matrix stats)

typedef __attribute__((ext_vector_type(4))) __fp16 half4;
typedef __attribute__((ext_vector_type(4))) float f32x4;

__device__ __forceinline__ f32x4 mfma16(half4 a, half4 b, f32x4 c) {
  return __builtin_amdgcn_mfma_f32_16x16x16f16(a, b, c, 0, 0, 0);
}

// ---------------- pass 1: bin edges by dst>>9, packed (src<<9)|dst_local ----------------
__global__ __launch_bounds__(256) void k_bin(const int* __restrict__ src,
                                             const int* __restrict__ dst,
                                             int* __restrict__ gcnt,
                                             unsigned int* __restrict__ binned, int E) {
  __shared__ int bcnt[256];
  const int t = threadIdx.x;
  const int e0 = blockIdx.x * EPB;
  bcnt[t] = 0;
  __syncthreads();
  for (int i = 0; i < EPB; i += 256) {
    int e = e0 + i + t;
    if (e < E) atomicAdd(&bcnt[dst[e] >> 9], 1);
  }
  __syncthreads();
  if (t < NBK) {
    int c = bcnt[t];
    bcnt[t] = c ? atomicAdd(&gcnt[t], c) : 0;
  }
  __syncthreads();
  for (int i = 0; i < EPB; i += 256) {
    int e = e0 + i + t;
    if (e < E) {
      int d = dst[e];
      int b = d >> 9;
      int pos = atomicAdd(&bcnt[b], 1);
      if (pos < CAP) binned[(size_t)b * CAP + pos] = ((unsigned int)src[e] << 9) | (d & 511);
    }
  }
}

// ---------------- pass 2: per-bucket local CSR (block-local writes) ----------------
__global__ __launch_bounds__(512) void k_csr(const unsigned int* __restrict__ binned,
                                             const int* __restrict__ gcnt,
                                             int* __restrict__ rowbeg,
                                             int* __restrict__ rowend,
                                             int* __restrict__ eidx, int N) {
  __shared__ int hist[512];
  __shared__ int cur[512];
  const int t = threadIdx.x;
  const int b = blockIdx.x;
  const size_t base = (size_t)b * CAP;
  int cnt = gcnt[b];
  if (cnt > CAP) cnt = CAP;
  hist[t] = 0;
  __syncthreads();
  for (int e = t; e < cnt; e += 512) atomicAdd(&hist[binned[base + e] & 511], 1);
  __syncthreads();
  const int own = hist[t];
  for (int o = 1; o < 512; o <<= 1) {
    int x = (t >= o) ? hist[t - o] : 0;
    __syncthreads();
    hist[t] += x;
    __syncthreads();
  }
  const int incl = hist[t];
  const int excl = incl - own;
  const int node = b * 512 + t;
  if (node < N) {
    rowbeg[node] = (int)base + excl;
    rowend[node] = (int)base + incl;
  }
  cur[t] = excl;
  __syncthreads();
  for (int e = t; e < cnt; e += 512) {
    unsigned int pk = binned[base + e];
    int pos = atomicAdd(&cur[pk & 511], 1);
    eidx[base + pos] = (int)(pk >> 9);
  }
}

// ------- k_stat: column sum/sumsq of M[N][64] -> PB[SB][128] f64, coalesced + ILP-4 -------
__global__ __launch_bounds__(256) void k_stat(const float* __restrict__ M, int N,
                                              double* __restrict__ PB) {
  const int t = threadIdx.x;
  const int c = t & 63;
  const int rr = t >> 6;  // 0..3
  const int j = blockIdx.x;
  const int STR = SB * 4;  // 1024 rows per sweep
  double s0 = 0, s1 = 0, s2 = 0, s3 = 0, q0 = 0, q1 = 0, q2 = 0, q3 = 0;
  int r = j * 4 + rr;
  for (; r + 3 * STR < N; r += 4 * STR) {
    float v0 = M[(size_t)r * 64 + c];
    float v1 = M[(size_t)(r + STR) * 64 + c];
    float v2 = M[(size_t)(r + 2 * STR) * 64 + c];
    float v3 = M[(size_t)(r + 3 * STR) * 64 + c];
    s0 += v0; q0 = fma((double)v0, (double)v0, q0);
    s1 += v1; q1 = fma((double)v1, (double)v1, q1);
    s2 += v2; q2 = fma((double)v2, (double)v2, q2);
    s3 += v3; q3 = fma((double)v3, (double)v3, q3);
  }
  for (; r < N; r += STR) {
    float v = M[(size_t)r * 64 + c];
    s0 += v; q0 = fma((double)v, (double)v, q0);
  }
  __shared__ double rs[256], rq[256];
  rs[t] = (s0 + s1) + (s2 + s3);
  rq[t] = (q0 + q1) + (q2 + q3);
  __syncthreads();
  if (t < 64)
    PB[(size_t)j * 128 + t] = rs[t] + rs[t + 64] + rs[t + 128] + rs[t + 192];
  else if (t < 128) {
    int c2 = t - 64;
    PB[(size_t)j * 128 + 64 + c2] = rq[c2] + rq[c2 + 64] + rq[c2 + 128] + rq[c2 + 192];
  }
}

// ------- k_red1: P[nblk][128] f32 -> PB[RB][128] f64 -------
__global__ __launch_bounds__(256) void k_red1(const float* __restrict__ P, int nblk,
                                              double* __restrict__ PB) {
  const int t = threadIdx.x;
  const int c = t & 127;
  const int half = t >> 7;  // 0 or 1
  const int j = blockIdx.x;
  const int STR = RB * 2;   // 256 rows per sweep
  double a0 = 0.0, a1 = 0.0, a2 = 0.0, a3 = 0.0;
  int r = j * 2 + half;
  for (; r + 3 * STR < nblk; r += 4 * STR) {
    a0 += (double)P[(size_t)r * 128 + c];
    a1 += (double)P[(size_t)(r + STR) * 128 + c];
    a2 += (double)P[(size_t)(r + 2 * STR) * 128 + c];
    a3 += (double)P[(size_t)(r + 3 * STR) * 128 + c];
  }
  for (; r < nblk; r += STR) a0 += (double)P[(size_t)r * 128 + c];
  double acc = (a0 + a1) + (a2 + a3);
  __shared__ double red[256];
  red[t] = acc;
  __syncthreads();
  if (t < 128) PB[(size_t)j * 128 + t] = red[t] + red[t + 128];
}

// ------- k_red2: finish PB[nrows][128], emit BN affine LUT (+ optional e0 = d@W1n) -------
// aff layout: [0..63]=a, [64..127]=d, [128..191]=e0 (only if W1n != null)
__global__ __launch_bounds__(256) void k_red2(const double* __restrict__ PB, int nrows,
                                              const float* __restrict__ g,
                                              const float* __restrict__ bt,
                                              double invN, float* __restrict__ aff,
                                              const float* __restrict__ W1n) {
  const int t = threadIdx.x;
  const int c = t & 127;
  const int half = t >> 7;
  double a0 = 0.0, a1 = 0.0, a2 = 0.0, a3 = 0.0;
  int j = half;
  for (; j + 6 < nrows; j += 8) {
    a0 += PB[(size_t)j * 128 + c];
    a1 += PB[(size_t)(j + 2) * 128 + c];
    a2 += PB[(size_t)(j + 4) * 128 + c];
    a3 += PB[(size_t)(j + 6) * 128 + c];
  }
  for (; j < nrows; j += 2) a0 += PB[(size_t)j * 128 + c];
  __shared__ double st[256];
  __shared__ float sd[64];
  st[t] = (a0 + a1) + (a2 + a3);
  __syncthreads();
  if (t < 128) st[t] = st[t] + st[t + 128];
  __syncthreads();
  if (t < 64) {
    double mu = st[t] * invN;
    double var = st[64 + t] * invN - mu * mu;
    double ai = (double)g[t] / sqrt(var + 1e-5);
    float dv = (float)((double)bt[t] - ai * mu);
    aff[t] = (float)ai;
    aff[64 + t] = dv;
    sd[t] = dv;
  }
  __syncthreads();
  if (W1n && t < 64) {
    float e = 0.f;
#pragma unroll
    for (int k = 0; k < 64; ++k) e = fmaf(sd[k], W1n[k * 64 + t], e);
    aff[128 + t] = e;
  }
}

__device__ __forceinline__ float rdl(float v, int l) {
  return __int_as_float(__builtin_amdgcn_readlane(__float_as_int(v), l));
}

// ========== k_vmmf: V = In @ (diag(a)*W1) -> half, MFMA 16x16x16_f16 ==========
// Wave tile: 16 rows x 64 cols, K=64 (4 ksteps x 4 col-tiles = 16 mfma).
// Lane maps (canonical CDNA): A[m][k]: m=l&15, k=4*(l>>4)+i+16*s.
// B[k][n]: n=l&15, same k. D[m][n]: n=l&15, m=(l>>4)*4+r.
template <bool XFORM>
__global__ __launch_bounds__(256) void k_vmmf(const float* __restrict__ In,
                                              const float* __restrict__ aff,
                                              const float* __restrict__ W,
                                              __half* __restrict__ Outh, int N) {
  const int l = threadIdx.x & 63;
  const int wid = (blockIdx.x * 256 + threadIdx.x) >> 6;
  const int T = N >> 4;  // tiles of 16 rows (N % 16 == 0)
  if (wid >= T) return;
  const int m = l & 15, g = l >> 4;
  const int row0 = wid * 16;

  half4 bf[4][4];  // [col-tile][kstep]
#pragma unroll
  for (int t = 0; t < 4; ++t)
#pragma unroll
    for (int s = 0; s < 4; ++s)
#pragma unroll
      for (int i = 0; i < 4; ++i) {
        const int k = 4 * g + 16 * s + i;
        float w = W[k * 64 + t * 16 + m];
        if (XFORM) w *= aff[k];
        bf[t][s][i] = (__fp16)w;
      }

  half4 af[4];
  const float* arow = In + (size_t)(row0 + m) * 64 + 4 * g;
#pragma unroll
  for (int s = 0; s < 4; ++s) {
    const float4 v = *(const float4*)(arow + 16 * s);
    af[s] = (half4){(__fp16)v.x, (__fp16)v.y, (__fp16)v.z, (__fp16)v.w};
  }

  f32x4 acc[4] = {{0.f, 0.f, 0.f, 0.f}, {0.f, 0.f, 0.f, 0.f},
                  {0.f, 0.f, 0.f, 0.f}, {0.f, 0.f, 0.f, 0.f}};
#pragma unroll
  for (int t = 0; t < 4; ++t)
#pragma unroll
    for (int s = 0; s < 4; ++s) acc[t] = mfma16(af[s], bf[t][s], acc[t]);

#pragma unroll
  for (int t = 0; t < 4; ++t)
#pragma unroll
    for (int r = 0; r < 4; ++r)
      Outh[(size_t)(row0 + g * 4 + r) * 64 + t * 16 + m] = __float2half(acc[t][r]);
}

// ========== k_mm1f: C = relu( relu(aff(Z)) @ W2 + b2 ), + stats(C) -> P[wave][128] ==========
// Same MFMA tile as k_vmmf; A = relu(a*Z+d) (inner BN), per-wave column stats via
// butterfly over lane groups (offsets 16/32), each lane writes its own P column.
__global__ __launch_bounds__(256) void k_mm1f(const float* __restrict__ Z,
                                              const float* __restrict__ aff,
                                              const float* __restrict__ W2,
                                              const float* __restrict__ b2,
                                              float* __restrict__ C,
                                              float* __restrict__ P, int N) {
  const int l = threadIdx.x & 63;
  const int wid = (blockIdx.x * 256 + threadIdx.x) >> 6;
  const int T = N >> 4;
  if (wid >= T) return;
  const int m = l & 15, g = l >> 4;
  const int row0 = wid * 16;

  half4 bf[4][4];
#pragma unroll
  for (int t = 0; t < 4; ++t)
#pragma unroll
    for (int s = 0; s < 4; ++s)
#pragma unroll
      for (int i = 0; i < 4; ++i) {
        const int k = 4 * g + 16 * s + i;
        bf[t][s][i] = (__fp16)W2[k * 64 + t * 16 + m];
      }

  half4 af[4];
  const float* arow = Z + (size_t)(row0 + m) * 64 + 4 * g;
#pragma unroll
  for (int s = 0; s < 4; ++s) {
    const float4 v = *(const float4*)(arow + 16 * s);
    const float4 fa = *(const float4*)(aff + 4 * g + 16 * s);
    const float4 fd = *(const float4*)(aff + 64 + 4 * g + 16 * s);
    const float x0 = fmaxf(fmaf(fa.x, v.x, fd.x), 0.f);
    const float x1 = fmaxf(fmaf(fa.y, v.y, fd.y), 0.f);
    const float x2 = fmaxf(fmaf(fa.z, v.z, fd.z), 0.f);
    const float x3 = fmaxf(fmaf(fa.w, v.w, fd.w), 0.f);
    af[s] = (half4){(__fp16)x0, (__fp16)x1, (__fp16)x2, (__fp16)x3};
  }

  f32x4 acc[4];
#pragma unroll
  for (int t = 0; t < 4; ++t) {
    const float bs = b2[t * 16 + m];
    acc[t] = (f32x4){bs, bs, bs, bs};
  }
#pragma unroll
  for (int t = 0; t < 4; ++t)
#pragma unroll
    for (int s = 0; s < 4; ++s) acc[t] = mfma16(af[s], bf[t][s], acc[t]);

  float sc[4], qc[4];
#pragma unroll
  for (int t = 0; t < 4; ++t) {
    float s_ = 0.f, q_ = 0.f;
#pragma unroll
    for (int r = 0; r < 4; ++r) {
      const float o = fmaxf(acc[t][r], 0.f);
      C[(size_t)(row0 + g * 4 + r) * 64 + t * 16 + m] = o;
      s_ += o;
      q_ = fmaf(o, o, q_);
    }
    sc[t] = s_;
    qc[t] = q_;
  }
#pragma unroll
  for (int t = 0; t < 4; ++t) {
    sc[t] += __shfl_xor(sc[t], 16);
    sc[t] += __shfl_xor(sc[t], 32);
    qc[t] += __shfl_xor(qc[t], 16);
    qc[t] += __shfl_xor(qc[t], 32);
  }
  // lane writes its own column: col = g*16 + m  (static-select over g)
  const float scw = (g == 0) ? sc[0] : (g == 1) ? sc[1] : (g == 2) ? sc[2] : sc[3];
  const float qcw = (g == 0) ? qc[0] : (g == 1) ? qc[1] : (g == 2) ? qc[2] : qc[3];
  P[(size_t)wid * 128 + g * 16 + m] = scw;
  P[(size_t)wid * 128 + 64 + g * 16 + m] = qcw;
}

// convert+accumulate 8 halfs (one uint4) into two float4 accumulators
__device__ __forceinline__ void h8_acc(const uint4 r, float4& a, float4& b) {
  const float2 f0 = __half22float2(*(const __half2*)&r.x);
  const float2 f1 = __half22float2(*(const __half2*)&r.y);
  const float2 f2 = __half22float2(*(const __half2*)&r.z);
  const float2 f3 = __half22float2(*(const __half2*)&r.w);
  a.x += f0.x; a.y += f0.y; a.z += f1.x; a.w += f1.y;
  b.x += f2.x; b.y += f2.y; b.z += f3.x; b.w += f3.y;
}

__device__ __forceinline__ uint4 h8_pair(const uint4 r0, const uint4 r1) {
  uint4 o;
  *(__half2*)&o.x = __hadd2(*(const __half2*)&r0.x, *(const __half2*)&r1.x);
  *(__half2*)&o.y = __hadd2(*(const __half2*)&r0.y, *(const __half2*)&r1.y);
  *(__half2*)&o.z = __hadd2(*(const __half2*)&r0.z, *(const __half2*)&r1.z);
  *(__half2*)&o.w = __hadd2(*(const __half2*)&r0.w, *(const __half2*)&r1.w);
  return o;
}

// ========== k_gather_h: Z[n] = sum_{n ∪ nb} v[m] + cnt_n*e0 + b1  (half rows, 128B) ==========
__global__ __launch_bounds__(256) void k_gather_h(const __half* __restrict__ V,
                                                  const int* __restrict__ rowbeg,
                                                  const int* __restrict__ rowend,
                                                  const int* __restrict__ eidx,
                                                  const float* __restrict__ e0,
                                                  const float* __restrict__ b1,
                                                  float* __restrict__ Out, int N) {
  const int node = blockIdx.x * 4 + (threadIdx.x >> 6);
  if (node >= N) return;
  const int lane = threadIdx.x & 63;
  const int grp = lane >> 3;   // edge group 0..7
  const int c8 = lane & 7;     // 16B chunk (8 halfs) within the row
  const int beg = rowbeg[node], end = rowend[node];

  float4 sA = make_float4(0.f, 0.f, 0.f, 0.f), sB = sA;
  if (grp == 0) {
    const uint4 r = *(const uint4*)(V + (size_t)node * 64 + c8 * 8);  // self (eps=0)
    h8_acc(r, sA, sB);
  }
  int i = beg + grp;
  for (; i + 8 < end; i += 16) {
    const int ea = eidx[i];
    const int eb = eidx[i + 8];
    const uint4 r0 = *(const uint4*)(V + (size_t)ea * 64 + c8 * 8);
    const uint4 r1 = *(const uint4*)(V + (size_t)eb * 64 + c8 * 8);
    h8_acc(h8_pair(r0, r1), sA, sB);
  }
  if (i < end) {
    const uint4 r = *(const uint4*)(V + (size_t)eidx[i] * 64 + c8 * 8);
    h8_acc(r, sA, sB);
  }
#pragma unroll
  for (int off = 8; off < 64; off <<= 1) {
    sA.x += __shfl_xor(sA.x, off);
    sA.y += __shfl_xor(sA.y, off);
    sA.z += __shfl_xor(sA.z, off);
    sA.w += __shfl_xor(sA.w, off);
    sB.x += __shfl_xor(sB.x, off);
    sB.y += __shfl_xor(sB.y, off);
    sB.z += __shfl_xor(sB.z, off);
    sB.w += __shfl_xor(sB.w, off);
  }
  if (grp == 0) {
    float4 oA = *(const float4*)(b1 + c8 * 8);
    float4 oB = *(const float4*)(b1 + c8 * 8 + 4);
    if (e0) {
      const float4 eA = *(const float4*)(e0 + c8 * 8);
      const float4 eB = *(const float4*)(e0 + c8 * 8 + 4);
      const float cnt = (float)(end - beg + 1);
      oA.x = fmaf(cnt, eA.x, oA.x);
      oA.y = fmaf(cnt, eA.y, oA.y);
      oA.z = fmaf(cnt, eA.z, oA.z);
      oA.w = fmaf(cnt, eA.w, oA.w);
      oB.x = fmaf(cnt, eB.x, oB.x);
      oB.y = fmaf(cnt, eB.y, oB.y);
      oB.z = fmaf(cnt, eB.z, oB.z);
      oB.w = fmaf(cnt, eB.w, oB.w);
    }
    oA.x += sA.x; oA.y += sA.y; oA.z += sA.z; oA.w += sA.w;
    oB.x += sB.x; oB.y += sB.y; oB.z += sB.z; oB.w += sB.w;
    *(float4*)(Out + (size_t)node * 64 + c8 * 8) = oA;
    *(float4*)(Out + (size_t)node * 64 + c8 * 8 + 4) = oB;
  }
}

// ========== k_mlp: readlane GEMM, kept ONLY for MODE 3 (final layer + log_softmax) ==========
template <int OUTC, int MODE>
__global__ __launch_bounds__(256) void k_mlp(const float* __restrict__ In,
                                             const float* __restrict__ aff,
                                             const float* __restrict__ W,
                                             const float* __restrict__ b,
                                             float* __restrict__ Out,
                                             float* __restrict__ P, int N) {
  const int lane = threadIdx.x & 63;
  const int wid = (blockIdx.x * 256 + threadIdx.x) >> 6;
  const int nw = NWAVES;
  const int G = N >> 2;

  const int cc = (lane < OUTC) ? lane : 0;
  float w[64];
#pragma unroll
  for (int k = 0; k < 64; ++k) w[k] = W[k * OUTC + cc];
  const float bias = b[cc];

  const float4 fa = *(const float4*)(aff + (lane & 15) * 4);
  const float4 fd = *(const float4*)(aff + 64 + (lane & 15) * 4);

  float sc = 0.f, qc = 0.f;

  int g = wid;
  float4 av = make_float4(0.f, 0.f, 0.f, 0.f);
  if (g < G) av = *(const float4*)(In + (size_t)g * 256 + lane * 4);
  for (; g < G; g += nw) {
    const int gn = g + nw;
    float4 nx = make_float4(0.f, 0.f, 0.f, 0.f);
    if (gn < G) nx = *(const float4*)(In + (size_t)gn * 256 + lane * 4);

    float4 v = av;
    v.x = fmaxf(fmaf(fa.x, v.x, fd.x), 0.f);
    v.y = fmaxf(fmaf(fa.y, v.y, fd.y), 0.f);
    v.z = fmaxf(fmaf(fa.z, v.z, fd.z), 0.f);
    v.w = fmaxf(fmaf(fa.w, v.w, fd.w), 0.f);
    const float a4[4] = {v.x, v.y, v.z, v.w};

    float acc0 = bias, acc1 = bias, acc2 = bias, acc3 = bias;
#pragma unroll
    for (int k = 0; k < 64; ++k) {
      const float ak = a4[k & 3];
      const int sl = k >> 2;
      acc0 = fmaf(rdl(ak, sl), w[k], acc0);
      acc1 = fmaf(rdl(ak, 16 + sl), w[k], acc1);
      acc2 = fmaf(rdl(ak, 32 + sl), w[k], acc2);
      acc3 = fmaf(rdl(ak, 48 + sl), w[k], acc3);
    }

    const int r0 = g * 4;
    if (MODE == 1) {
      const float o0 = fmaxf(acc0, 0.f), o1 = fmaxf(acc1, 0.f);
      const float o2 = fmaxf(acc2, 0.f), o3 = fmaxf(acc3, 0.f);
      Out[(size_t)(r0 + 0) * OUTC + lane] = o0;
      Out[(size_t)(r0 + 1) * OUTC + lane] = o1;
      Out[(size_t)(r0 + 2) * OUTC + lane] = o2;
      Out[(size_t)(r0 + 3) * OUTC + lane] = o3;
      sc += o0 + o1 + o2 + o3;
      qc = fmaf(o0, o0, qc);
      qc = fmaf(o1, o1, qc);
      qc = fmaf(o2, o2, qc);
      qc = fmaf(o3, o3, qc);
    } else {  // MODE 3: log_softmax over OUTC cols (lanes >= OUTC masked out)
      float m0 = (lane < OUTC) ? acc0 : -1e30f;
      float m1 = (lane < OUTC) ? acc1 : -1e30f;
      float m2 = (lane < OUTC) ? acc2 : -1e30f;
      float m3 = (lane < OUTC) ? acc3 : -1e30f;
#pragma unroll
      for (int off = 32; off; off >>= 1) {
        m0 = fmaxf(m0, __shfl_xor(m0, off));
        m1 = fmaxf(m1, __shfl_xor(m1, off));
        m2 = fmaxf(m2, __shfl_xor(m2, off));
        m3 = fmaxf(m3, __shfl_xor(m3, off));
      }
      float s0 = (lane < OUTC) ? expf(acc0 - m0) : 0.f;
      float s1 = (lane < OUTC) ? expf(acc1 - m1) : 0.f;
      float s2 = (lane < OUTC) ? expf(acc2 - m2) : 0.f;
      float s3 = (lane < OUTC) ? expf(acc3 - m3) : 0.f;
#pragma unroll
      for (int off = 32; off; off >>= 1) {
        s0 += __shfl_xor(s0, off);
        s1 += __shfl_xor(s1, off);
        s2 += __shfl_xor(s2, off);
        s3 += __shfl_xor(s3, off);
      }
      if (lane < OUTC) {
        Out[(size_t)(r0 + 0) * OUTC + lane] = acc0 - (m0 + logf(s0));
        Out[(size_t)(r0 + 1) * OUTC + lane] = acc1 - (m1 + logf(s1));
        Out[(size_t)(r0 + 2) * OUTC + lane] = acc2 - (m2 + logf(s2));
        Out[(size_t)(r0 + 3) * OUTC + lane] = acc3 - (m3 + logf(s3));
      }
    }
    av = nx;
  }

  if (MODE == 1) {
    P[(size_t)wid * 128 + lane] = sc;
    P[(size_t)wid * 128 + 64 + lane] = qc;
  }
}

extern "C" void kernel_launch(void* const* d_in, const int* in_sizes, int n_in,
                              void* d_out, int out_size, void* d_ws, size_t ws_size,
                              hipStream_t stream) {
  const float* x = (const float*)d_in[0];
  const int* src = (const int*)d_in[1];
  const int* dst = (const int*)d_in[2];
  const float *W1[3], *b1[3], *g[3], *bt[3], *W2[3], *b2[3];
  for (int i = 0; i < 3; ++i) {
    W1[i] = (const float*)d_in[3 + i * 6 + 0];
    b1[i] = (const float*)d_in[3 + i * 6 + 1];
    g[i] = (const float*)d_in[3 + i * 6 + 2];
    bt[i] = (const float*)d_in[3 + i * 6 + 3];
    W2[i] = (const float*)d_in[3 + i * 6 + 4];
    b2[i] = (const float*)d_in[3 + i * 6 + 5];
  }
  const float* bng[2] = {(const float*)d_in[21], (const float*)d_in[23]};
  const float* bnb[2] = {(const float*)d_in[22], (const float*)d_in[24]};

  const int N = NN, E = NE;
  const size_t N64 = (size_t)N * 64;
  const int ggat = N / 4;            // 25000 blocks (1 node per wave)
  const int T = N / 16;              // 6250 MFMA tiles (16 rows each)
  const int gmf = (T + 3) / 4;       // 1563 blocks (4 waves, 1 tile per wave)
  const int gmlp = NWAVES / 4;       // 2048 blocks (grid-stride, MODE 3 only)

  // workspace layout (~89 MB)
  char* p = (char*)d_ws;
  float* B = (float*)p; p += N64 * 4;            // Z buffer (fp32)
  float* C = (float*)p; p += N64 * 4;            // relu(h) buffer (fp32)
  __half* V = (__half*)p; p += N64 * 2;          // v rows (half, 128B/row)
  int* gcnt = (int*)p; p += 256 * 4;             // bucket counters (memset)
  float* aff = (float*)p; p += 192 * 4;          // BN LUT: a[64], d[64], e0[64]
  float* P = (float*)p; p += (size_t)NWAVES * 128 * 4;  // per-wave partials (4MB)
  double* PB = (double*)p; p += (size_t)SB * 128 * 8;   // stats partials (256KB)
  int* rowbeg = (int*)p; p += (size_t)N * 4;
  int* rowend = (int*)p; p += (size_t)N * 4;
  unsigned int* binned = (unsigned int*)p; p += (size_t)NBK * CAP * 4;
  int* eidx = (int*)p; p += (size_t)NBK * CAP * 4;

  const double invN = 1.0 / (double)N;

  hipMemsetAsync(gcnt, 0, 256 * 4, stream);

  // ---- CSR build (bucketed counting sort, block-local writes) ----
  k_bin<<<(E + EPB - 1) / EPB, 256, 0, stream>>>(src, dst, gcnt, binned, E);
  k_csr<<<NBK, 512, 0, stream>>>(binned, gcnt, rowbeg, rowend, eidx, N);

  // ---- layer 0:  v0 = x @ W1[0];  Z0[n] = sum v0 + b1[0] ----
  k_vmmf<false><<<gmf, 256, 0, stream>>>(x, nullptr, W1[0], V, N);
  k_gather_h<<<ggat, 256, 0, stream>>>(V, rowbeg, rowend, eidx, (const float*)nullptr, b1[0], B, N);
  k_stat<<<SB, 256, 0, stream>>>(B, N, PB);
  k_red2<<<1, 256, 0, stream>>>(PB, SB, g[0], bt[0], invN, aff, (const float*)nullptr);
  k_mm1f<<<gmf, 256, 0, stream>>>(B, aff, W2[0], b2[0], C, P, N);
  k_red1<<<RB, 256, 0, stream>>>(P, T, PB);
  k_red2<<<1, 256, 0, stream>>>(PB, RB, bng[0], bnb[0], invN, aff, W1[1]);  // outer aff + e0

  // ---- layer 1:  v = C @ diag(a)W1[1];  Z[n] = sum v + cnt*e0 + b1[1] ----
  k_vmmf<true><<<gmf, 256, 0, stream>>>(C, aff, W1[1], V, N);
  k_gather_h<<<ggat, 256, 0, stream>>>(V, rowbeg, rowend, eidx, aff + 128, b1[1], B, N);
  k_stat<<<SB, 256, 0, stream>>>(B, N, PB);
  k_red2<<<1, 256, 0, stream>>>(PB, SB, g[1], bt[1], invN, aff, (const float*)nullptr);
  k_mm1f<<<gmf, 256, 0, stream>>>(B, aff, W2[1], b2[1], C, P, N);
  k_red1<<<RB, 256, 0, stream>>>(P, T, PB);
  k_red2<<<1, 256, 0, stream>>>(PB, RB, bng[1], bnb[1], invN, aff, W1[2]);  // outer aff + e0

  // ---- layer 2 (final: fused log_softmax via readlane MODE 3) ----
  k_vmmf<true><<<gmf, 256, 0, stream>>>(C, aff, W1[2], V, N);
  k_gather_h<<<ggat, 256, 0, stream>>>(V, rowbeg, rowend, eidx, aff + 128, b1[2], B, N);
  k_stat<<<SB, 256, 0, stream>>>(B, N, PB);
  k_red2<<<1, 256, 0, stream>>>(PB, SB, g[2], bt[2], invN, aff, (const float*)nullptr);
  k_mlp<40, 3><<<gmlp, 256, 0, stream>>>(B, aff, W2[2], b2[2], (float*)d_out, nullptr, N);
}